// Round 9
// baseline (517.462 us; speedup 1.0000x reference)
//
#include <hip/hip_runtime.h>

#define PCH   32
#define NWT   19
#define SCH   2048

typedef unsigned short ushort_t;
typedef __attribute__((ext_vector_type(8))) short bf16x8;
typedef __attribute__((ext_vector_type(4))) float f32x4;

__device__ __forceinline__ float bf2f(unsigned int v) {
    return __uint_as_float(v << 16);
}
__device__ __forceinline__ unsigned int f2bu(float f) {
    unsigned int u = __float_as_uint(f);
    return (u + 0x7fffu + ((u >> 16) & 1u)) >> 16;
}
__device__ __forceinline__ void unpack8(uint4 u, float* f) {
    f[0] = bf2f(u.x & 0xffff); f[1] = bf2f(u.x >> 16);
    f[2] = bf2f(u.y & 0xffff); f[3] = bf2f(u.y >> 16);
    f[4] = bf2f(u.z & 0xffff); f[5] = bf2f(u.z >> 16);
    f[6] = bf2f(u.w & 0xffff); f[7] = bf2f(u.w >> 16);
}
__device__ __forceinline__ uint4 pack8(const float* f) {
    uint4 p;
    p.x = f2bu(f[0]) | (f2bu(f[1]) << 16);
    p.y = f2bu(f[2]) | (f2bu(f[3]) << 16);
    p.z = f2bu(f[4]) | (f2bu(f[5]) << 16);
    p.w = f2bu(f[6]) | (f2bu(f[7]) << 16);
    return p;
}
__device__ __forceinline__ void fma8(uint4 u, float c, float* a) {
    a[0] = fmaf(c, bf2f(u.x & 0xffff), a[0]);
    a[1] = fmaf(c, bf2f(u.x >> 16), a[1]);
    a[2] = fmaf(c, bf2f(u.y & 0xffff), a[2]);
    a[3] = fmaf(c, bf2f(u.y >> 16), a[3]);
    a[4] = fmaf(c, bf2f(u.z & 0xffff), a[4]);
    a[5] = fmaf(c, bf2f(u.z >> 16), a[5]);
    a[6] = fmaf(c, bf2f(u.w & 0xffff), a[6]);
    a[7] = fmaf(c, bf2f(u.w >> 16), a[7]);
}
__device__ __forceinline__ float dot8(uint4 u, const float* q) {
    float d = q[0] * bf2f(u.x & 0xffff);
    d = fmaf(q[1], bf2f(u.x >> 16), d);
    d = fmaf(q[2], bf2f(u.y & 0xffff), d);
    d = fmaf(q[3], bf2f(u.y >> 16), d);
    d = fmaf(q[4], bf2f(u.z & 0xffff), d);
    d = fmaf(q[5], bf2f(u.z >> 16), d);
    d = fmaf(q[6], bf2f(u.w & 0xffff), d);
    d = fmaf(q[7], bf2f(u.w >> 16), d);
    return d;
}

struct WtPack {
    const float* src[NWT];
    unsigned long long off[NWT];
    int K[NWT];
};

// ---------------- merged setup: wconv + seg_bounds + edge_deg ----------------
__global__ void setup_mega_kernel(WtPack p, ushort_t* __restrict__ base,
                                  const int* __restrict__ batch,
                                  int* __restrict__ bstart, int* __restrict__ bend, int N,
                                  const int* __restrict__ dst, int* __restrict__ degi, int E)
{
    int bx = blockIdx.x, tid = threadIdx.x;
    int nseg = (N + 255) >> 8;
    if (bx < 608) {
        int a = bx >> 5, xp = bx & 31;
        const float* s = p.src[a];
        ushort_t* d = base + p.off[a];
        int K = p.K[a];
        int total = K * 128;
        for (int i = xp * 256 + tid; i < total; i += 32 * 256) {
            int k = i >> 7, n = i & 127;
            d[n * K + k] = (ushort_t)f2bu(s[i]);
        }
    } else if (bx < 608 + nseg) {
        int n = (bx - 608) * 256 + tid;
        if (n >= N) return;
        int b = batch[n];
        if (n == 0) bstart[b] = 0;
        else {
            int pb = batch[n - 1];
            if (pb != b) { bstart[b] = n; bend[pb] = n; }
        }
        if (n == N - 1) bend[b] = N;
    } else {
        int e = (bx - 608 - nseg) * 256 + tid;
        if (e < E) atomicAdd(&degi[dst[e]], 1);
    }
}

// ---------- parallel 3-phase scan ----------
__global__ void scan1_kernel(const int* __restrict__ degi, int* __restrict__ rowptr,
                             int* __restrict__ bsum, int n) {
    __shared__ int sh[256];
    int tid = threadIdx.x;
    int base = blockIdx.x * SCH + tid * 8;
    int loc[8]; int s = 0;
#pragma unroll
    for (int j = 0; j < 8; j++) {
        int idx = base + j;
        int v = (idx < n) ? degi[idx] : 0;
        s += v; loc[j] = s;
    }
    sh[tid] = s;
    __syncthreads();
    for (int off = 1; off < 256; off <<= 1) {
        int t = (tid >= off) ? sh[tid - off] : 0;
        __syncthreads();
        sh[tid] += t;
        __syncthreads();
    }
    int prev = (tid > 0) ? sh[tid - 1] : 0;
#pragma unroll
    for (int j = 0; j < 8; j++) {
        int idx = base + j;
        if (idx < n) rowptr[idx + 1] = prev + loc[j];
    }
    if (tid == 255) bsum[blockIdx.x] = sh[255];
}
__global__ void scan2_kernel(int* __restrict__ bsum, int nb) {
    __shared__ int sh[256];
    int tid = threadIdx.x;
    sh[tid] = (tid < nb) ? bsum[tid] : 0;
    __syncthreads();
    for (int off = 1; off < 256; off <<= 1) {
        int t = (tid >= off) ? sh[tid - off] : 0;
        __syncthreads();
        sh[tid] += t;
        __syncthreads();
    }
    if (tid < nb) bsum[tid] = (tid > 0) ? sh[tid - 1] : 0;
}

// ---------- fp32-A MFMA GEMM + fused LN+ReLU + router partials (device) ----------
struct EncCfg {
    const float* A; int lda; int K;
    const ushort_t* Wt; ushort_t* Cb;           // Cb stride 256
    const float* bias; const float* g; const float* be;
    const float* rW; float* logits;
};

__device__ __forceinline__ void gemm_f32_ln_dev(ushort_t (*As)[40], ushort_t (*Bs)[40],
                                                const EncCfg c, int bx, int M)
{
    const int tid = threadIdx.x;
    const int m0 = bx * 64;
    const int lane = tid & 63;
    const int wv = tid >> 6;
    const int q = lane >> 4;
    const int l16 = lane & 15;
    const int sar = tid >> 2;
    const int sak = (tid & 3) << 3;
    const int sbn = tid >> 1;
    const int sbk = (tid & 1) << 4;
    const int K = c.K;
    const bool arow_ok = (m0 + sar) < M;
    const float* Arow = c.A + (size_t)(m0 + sar) * c.lda;
    const ushort_t* Wrow = c.Wt + (size_t)sbn * K;

    f32x4 acc[8];
#pragma unroll
    for (int t = 0; t < 8; t++) acc[t] = (f32x4){0.f, 0.f, 0.f, 0.f};

    for (int k0 = 0; k0 < K; k0 += 32) {
        uint4 apk;
        if (arow_ok && k0 + sak + 8 <= K) {
            float4 p0 = *(const float4*)(Arow + k0 + sak);
            float4 p1 = *(const float4*)(Arow + k0 + sak + 4);
            apk.x = f2bu(p0.x) | (f2bu(p0.y) << 16);
            apk.y = f2bu(p0.z) | (f2bu(p0.w) << 16);
            apk.z = f2bu(p1.x) | (f2bu(p1.y) << 16);
            apk.w = f2bu(p1.z) | (f2bu(p1.w) << 16);
        } else {
            unsigned int t4[4] = {0, 0, 0, 0};
            for (int j = 0; j < 8; j++) {
                int k = k0 + sak + j;
                unsigned int bv = (arow_ok && k < K) ? f2bu(Arow[k]) : 0u;
                t4[j >> 1] |= bv << ((j & 1) * 16);
            }
            apk = make_uint4(t4[0], t4[1], t4[2], t4[3]);
        }
        uint4 b0, b1;
        if (k0 + sbk + 16 <= K) {
            b0 = *(const uint4*)(Wrow + k0 + sbk);
            b1 = *(const uint4*)(Wrow + k0 + sbk + 8);
        } else {
            unsigned int t8[8] = {0, 0, 0, 0, 0, 0, 0, 0};
            for (int j = 0; j < 16; j++) {
                int k = k0 + sbk + j;
                unsigned int bv = (k < K) ? (unsigned int)Wrow[k] : 0u;
                t8[j >> 1] |= bv << ((j & 1) * 16);
            }
            b0 = make_uint4(t8[0], t8[1], t8[2], t8[3]);
            b1 = make_uint4(t8[4], t8[5], t8[6], t8[7]);
        }
        __syncthreads();
        *(uint4*)&As[sar][sak] = apk;
        *(uint4*)&Bs[sbn][sbk] = b0;
        *(uint4*)&Bs[sbn][sbk + 8] = b1;
        __syncthreads();
        bf16x8 af = *(const bf16x8*)&As[16 * wv + l16][q * 8];
#pragma unroll
        for (int t = 0; t < 8; t++) {
            bf16x8 bf = *(const bf16x8*)&Bs[t * 16 + l16][q * 8];
            acc[t] = __builtin_amdgcn_mfma_f32_16x16x32_bf16(af, bf, acc[t], 0, 0, 0);
        }
    }
    const int row_base = m0 + 16 * wv + q * 4;
#pragma unroll
    for (int t = 0; t < 8; t++) {
        float bb = c.bias[t * 16 + l16];
#pragma unroll
        for (int r = 0; r < 4; r++) acc[t][r] += bb;
    }
    float mean[4], inv[4];
#pragma unroll
    for (int r = 0; r < 4; r++) {
        float s = 0.f, sq = 0.f;
#pragma unroll
        for (int t = 0; t < 8; t++) { float v = acc[t][r]; s += v; sq = fmaf(v, v, sq); }
#pragma unroll
        for (int off = 1; off <= 8; off <<= 1) { s += __shfl_xor(s, off); sq += __shfl_xor(sq, off); }
        mean[r] = s * (1.f / 128.f);
        float var = sq * (1.f / 128.f) - mean[r] * mean[r];
        inv[r] = rsqrtf(var + 1e-5f);
    }
    float rl0[4] = {0, 0, 0, 0}, rl1[4] = {0, 0, 0, 0};
    float rl2[4] = {0, 0, 0, 0}, rl3[4] = {0, 0, 0, 0};
#pragma unroll
    for (int t = 0; t < 8; t++) {
        int col = t * 16 + l16;
        float gg = c.g[col], b2 = c.be[col];
        float4 rw = *(const float4*)(c.rW + col * 4);
#pragma unroll
        for (int r = 0; r < 4; r++) {
            float y = fmaxf(fmaf((acc[t][r] - mean[r]) * inv[r], gg, b2), 0.f);
            rl0[r] = fmaf(y, rw.x, rl0[r]);
            rl1[r] = fmaf(y, rw.y, rl1[r]);
            rl2[r] = fmaf(y, rw.z, rl2[r]);
            rl3[r] = fmaf(y, rw.w, rl3[r]);
            float other = __shfl_xor(y, 1);
            int row = row_base + r;
            if (!(l16 & 1) && row < M) {
                unsigned int pk = f2bu(y) | (f2bu(other) << 16);
                *(unsigned int*)(c.Cb + (size_t)row * 256 + col) = pk;
            }
        }
    }
#pragma unroll
    for (int r = 0; r < 4; r++) {
#pragma unroll
        for (int off = 1; off <= 8; off <<= 1) {
            rl0[r] += __shfl_xor(rl0[r], off);
            rl1[r] += __shfl_xor(rl1[r], off);
            rl2[r] += __shfl_xor(rl2[r], off);
            rl3[r] += __shfl_xor(rl3[r], off);
        }
        int row = row_base + r;
        if (l16 == 0 && row < M)
            *(float4*)(c.logits + (size_t)row * 4) = make_float4(rl0[r], rl1[r], rl2[r], rl3[r]);
    }
}

// ---------- merged scan3 + encoder GEMMs ----------
__global__ __launch_bounds__(256)
void scan3_enc_kernel(int* __restrict__ rowptr, const int* __restrict__ bsum,
                      const int* __restrict__ degi,
                      float* __restrict__ dinv, float* __restrict__ dinvl, int N,
                      EncCfg c0, EncCfg c1)
{
    __shared__ ushort_t As[64][40];
    __shared__ ushort_t Bs[128][40];
    int bx = blockIdx.x;
    int ns3 = (N + 255) >> 8;
    int gG = (N + 63) >> 6;
    if (bx < ns3) {
        int i = bx * 256 + threadIdx.x;
        if (i == 0) rowptr[0] = 0;
        if (i < N) {
            rowptr[i + 1] += bsum[i / SCH];
            float deg = (float)degi[i];
            dinv[i] = (deg > 0.f) ? rsqrtf(fmaxf(deg, 1.f)) : 0.f;
            dinvl[i] = rsqrtf(deg + 1.f);
        }
        return;
    }
    int b2 = bx - ns3;
    if (b2 < gG) gemm_f32_ln_dev(As, Bs, c0, b2, N);
    else gemm_f32_ln_dev(As, Bs, c1, b2 - gG, N);
}

// ---------- device: fuse GEMM K=256 with LN+ReLU epilogue ----------
__device__ __forceinline__ void gemm_ln256_dev(ushort_t (*As)[40], ushort_t (*Bs)[40],
                                               const ushort_t* __restrict__ A,
                                               const ushort_t* __restrict__ Wt,
                                               ushort_t* __restrict__ Cb, int M,
                                               const float* __restrict__ bias,
                                               const float* __restrict__ g,
                                               const float* __restrict__ be, int bx)
{
    const int K = 256;
    const int tid = threadIdx.x;
    const int m0 = bx * 64;
    const int lane = tid & 63;
    const int wv = tid >> 6;
    const int q = lane >> 4;
    const int l16 = lane & 15;
    const int sar = tid >> 2;
    const int sak = (tid & 3) << 3;
    const int sbn = tid >> 1;
    const int sbk = (tid & 1) << 4;
    const bool arow_ok = (m0 + sar) < M;
    const ushort_t* Arow = A + (size_t)(m0 + sar) * K;
    const ushort_t* Wrow = Wt + (size_t)sbn * K;

    f32x4 acc[8];
#pragma unroll
    for (int t = 0; t < 8; t++) acc[t] = (f32x4){0.f, 0.f, 0.f, 0.f};

#pragma unroll
    for (int k0 = 0; k0 < K; k0 += 32) {
        uint4 apk = arow_ok ? *(const uint4*)(Arow + k0 + sak) : make_uint4(0, 0, 0, 0);
        uint4 b0 = *(const uint4*)(Wrow + k0 + sbk);
        uint4 b1 = *(const uint4*)(Wrow + k0 + sbk + 8);
        __syncthreads();
        *(uint4*)&As[sar][sak] = apk;
        *(uint4*)&Bs[sbn][sbk] = b0;
        *(uint4*)&Bs[sbn][sbk + 8] = b1;
        __syncthreads();
        bf16x8 af = *(const bf16x8*)&As[16 * wv + l16][q * 8];
#pragma unroll
        for (int t = 0; t < 8; t++) {
            bf16x8 bf = *(const bf16x8*)&Bs[t * 16 + l16][q * 8];
            acc[t] = __builtin_amdgcn_mfma_f32_16x16x32_bf16(af, bf, acc[t], 0, 0, 0);
        }
    }
    const int row_base = m0 + 16 * wv + q * 4;
#pragma unroll
    for (int t = 0; t < 8; t++) {
        float bb = bias[t * 16 + l16];
#pragma unroll
        for (int r = 0; r < 4; r++) acc[t][r] += bb;
    }
    float mean[4], inv[4];
#pragma unroll
    for (int r = 0; r < 4; r++) {
        float s = 0.f, sq = 0.f;
#pragma unroll
        for (int t = 0; t < 8; t++) { float v = acc[t][r]; s += v; sq = fmaf(v, v, sq); }
#pragma unroll
        for (int off = 1; off <= 8; off <<= 1) { s += __shfl_xor(s, off); sq += __shfl_xor(sq, off); }
        mean[r] = s * (1.f / 128.f);
        float var = sq * (1.f / 128.f) - mean[r] * mean[r];
        inv[r] = rsqrtf(var + 1e-5f);
    }
#pragma unroll
    for (int t = 0; t < 8; t++) {
        int col = t * 16 + l16;
        float gg = g[col], b2 = be[col];
#pragma unroll
        for (int r = 0; r < 4; r++) {
            float y = fmaxf(fmaf((acc[t][r] - mean[r]) * inv[r], gg, b2), 0.f);
            float other = __shfl_xor(y, 1);
            int row = row_base + r;
            if (!(l16 & 1) && row < M) {
                unsigned int pk = f2bu(y) | (f2bu(other) << 16);
                *(unsigned int*)(Cb + (size_t)row * 128 + col) = pk;
            }
        }
    }
}

// ---------- merged: fuse GEMM + csr_fill + router top-k ----------
__global__ __launch_bounds__(256)
void ln_csr_topk_kernel(const ushort_t* __restrict__ A, const ushort_t* __restrict__ Wt,
                        ushort_t* __restrict__ Cb, int N,
                        const float* __restrict__ bias,
                        const float* __restrict__ g, const float* __restrict__ be,
                        const int* __restrict__ src, const int* __restrict__ dst,
                        const int* __restrict__ rowptr, int* __restrict__ cursor,
                        int* __restrict__ csr,
                        const float* __restrict__ dinv, const float* __restrict__ dinvl,
                        float* __restrict__ ecA, float* __restrict__ ecB, int E,
                        const float* __restrict__ la, const float* __restrict__ lb,
                        float* __restrict__ gates)
{
    __shared__ ushort_t As[64][40];
    __shared__ ushort_t Bs[128][40];
    int bx = blockIdx.x;
    int gG = (N + 63) >> 6;
    int nedge = (E + 255) >> 8;
    if (bx < gG) {
        gemm_ln256_dev(As, Bs, A, Wt, Cb, N, bias, g, be, bx);
        return;
    }
    if (bx < gG + nedge) {
        int e = (bx - gG) * 256 + threadIdx.x;
        if (e >= E) return;
        int d = dst[e];
        int s = src[e];
        int pos = atomicAdd(&cursor[d], 1);
        int o = rowptr[d] + pos;
        csr[o] = s;
        ecA[o] = dinv[d] * dinv[s];
        ecB[o] = dinvl[d] * dinvl[s];
        return;
    }
    int n = (bx - gG - nedge) * 256 + threadIdx.x;
    if (n >= N) return;
    float4 a = *(const float4*)(la + (size_t)n * 4);
    float4 b = *(const float4*)(lb + (size_t)n * 4);
    float l[4] = {(a.x + b.x) * (1.f / 1.5f), (a.y + b.y) * (1.f / 1.5f),
                  (a.z + b.z) * (1.f / 1.5f), (a.w + b.w) * (1.f / 1.5f)};
    float mx = fmaxf(fmaxf(l[0], l[1]), fmaxf(l[2], l[3]));
    float e4[4], ssum = 0.f;
#pragma unroll
    for (int i = 0; i < 4; i++) { e4[i] = expf(l[i] - mx); ssum += e4[i]; }
    float p[4];
#pragma unroll
    for (int i = 0; i < 4; i++) p[i] = e4[i] / ssum;
    int i0 = 0;
    for (int i = 1; i < 4; i++) if (p[i] > p[i0]) i0 = i;
    int i1 = -1;
    for (int i = 0; i < 4; i++) {
        if (i == i0) continue;
        if (i1 < 0 || p[i] > p[i1]) i1 = i;
    }
    float wsum = fmaxf(p[i0] + p[i1], 1e-9f);
    float gg[4] = {0.f, 0.f, 0.f, 0.f};
    gg[i0] = p[i0] / wsum;
    gg[i1] = p[i1] / wsum;
    *(float4*)(gates + (size_t)n * 4) = make_float4(gg[0], gg[1], gg[2], gg[3]);
}

// ---------- device: bf16 LDS GEMM (K templated), plain epilogue ----------
template <int K>
__device__ __forceinline__ void gemm_bf_dev(ushort_t (*As)[40], ushort_t (*Bs)[40],
                                            const ushort_t* __restrict__ A,
                                            const ushort_t* __restrict__ Wt,
                                            ushort_t* __restrict__ Cb, int M,
                                            const float* __restrict__ bias, int relu, int bx)
{
    const int tid = threadIdx.x;
    const int m0 = bx * 64;
    const int lane = tid & 63;
    const int wv = tid >> 6;
    const int q = lane >> 4;
    const int l16 = lane & 15;
    const int sar = tid >> 2;
    const int sak = (tid & 3) << 3;
    const int sbn = tid >> 1;
    const int sbk = (tid & 1) << 4;
    const bool arow_ok = (m0 + sar) < M;
    const ushort_t* Arow = A + (size_t)(m0 + sar) * K;
    const ushort_t* Wrow = Wt + (size_t)sbn * K;

    f32x4 acc[8];
#pragma unroll
    for (int t = 0; t < 8; t++) acc[t] = (f32x4){0.f, 0.f, 0.f, 0.f};

#pragma unroll
    for (int k0 = 0; k0 < K; k0 += 32) {
        uint4 apk = arow_ok ? *(const uint4*)(Arow + k0 + sak) : make_uint4(0, 0, 0, 0);
        uint4 b0 = *(const uint4*)(Wrow + k0 + sbk);
        uint4 b1 = *(const uint4*)(Wrow + k0 + sbk + 8);
        __syncthreads();
        *(uint4*)&As[sar][sak] = apk;
        *(uint4*)&Bs[sbn][sbk] = b0;
        *(uint4*)&Bs[sbn][sbk + 8] = b1;
        __syncthreads();
        bf16x8 af = *(const bf16x8*)&As[16 * wv + l16][q * 8];
#pragma unroll
        for (int t = 0; t < 8; t++) {
            bf16x8 bf = *(const bf16x8*)&Bs[t * 16 + l16][q * 8];
            acc[t] = __builtin_amdgcn_mfma_f32_16x16x32_bf16(af, bf, acc[t], 0, 0, 0);
        }
    }
#pragma unroll
    for (int t = 0; t < 8; t++) {
        int col = t * 16 + l16;
        float bb = bias ? bias[col] : 0.f;
#pragma unroll
        for (int r = 0; r < 4; r++) {
            int row = m0 + 16 * wv + q * 4 + r;
            float val = acc[t][r] + bb;
            if (relu) val = fmaxf(val, 0.f);
            float other = __shfl_xor(val, 1);
            if (!(lane & 1) && row < M) {
                unsigned int pk = f2bu(val) | (f2bu(other) << 16);
                *(unsigned int*)(Cb + (size_t)row * 128 + col) = pk;
            }
        }
    }
}

// ---------- device: bf16 LDS GEMM with output stride (K=128), plain bias ----------
__device__ __forceinline__ void gemm_bfs_dev(ushort_t (*As)[40], ushort_t (*Bs)[40],
                                             const ushort_t* __restrict__ A,
                                             const ushort_t* __restrict__ Wt,
                                             ushort_t* __restrict__ Cb, int ldc, int M,
                                             const float* __restrict__ bias, int bx)
{
    const int K = 128;
    const int tid = threadIdx.x;
    const int m0 = bx * 64;
    const int lane = tid & 63;
    const int wv = tid >> 6;
    const int q = lane >> 4;
    const int l16 = lane & 15;
    const int sar = tid >> 2;
    const int sak = (tid & 3) << 3;
    const int sbn = tid >> 1;
    const int sbk = (tid & 1) << 4;
    const bool arow_ok = (m0 + sar) < M;
    const ushort_t* Arow = A + (size_t)(m0 + sar) * K;
    const ushort_t* Wrow = Wt + (size_t)sbn * K;

    f32x4 acc[8];
#pragma unroll
    for (int t = 0; t < 8; t++) acc[t] = (f32x4){0.f, 0.f, 0.f, 0.f};

#pragma unroll
    for (int k0 = 0; k0 < K; k0 += 32) {
        uint4 apk = arow_ok ? *(const uint4*)(Arow + k0 + sak) : make_uint4(0, 0, 0, 0);
        uint4 b0 = *(const uint4*)(Wrow + k0 + sbk);
        uint4 b1 = *(const uint4*)(Wrow + k0 + sbk + 8);
        __syncthreads();
        *(uint4*)&As[sar][sak] = apk;
        *(uint4*)&Bs[sbn][sbk] = b0;
        *(uint4*)&Bs[sbn][sbk + 8] = b1;
        __syncthreads();
        bf16x8 af = *(const bf16x8*)&As[16 * wv + l16][q * 8];
#pragma unroll
        for (int t = 0; t < 8; t++) {
            bf16x8 bf = *(const bf16x8*)&Bs[t * 16 + l16][q * 8];
            acc[t] = __builtin_amdgcn_mfma_f32_16x16x32_bf16(af, bf, acc[t], 0, 0, 0);
        }
    }
#pragma unroll
    for (int t = 0; t < 8; t++) {
        int col = t * 16 + l16;
        float bb = bias[col];
#pragma unroll
        for (int r = 0; r < 4; r++) {
            int row = m0 + 16 * wv + q * 4 + r;
            float val = acc[t][r] + bb;
            float other = __shfl_xor(val, 1);
            if (!(lane & 1) && row < M) {
                unsigned int pk = f2bu(val) | (f2bu(other) << 16);
                *(unsigned int*)(Cb + (size_t)row * ldc + col) = pk;
            }
        }
    }
}

// ---------- device: dual GEMM C = A1@W1 + A2@W2 ----------
__device__ __forceinline__ void gemm_dual_dev(ushort_t (*As)[40], ushort_t (*Bs)[40],
                                              const ushort_t* __restrict__ A1,
                                              const ushort_t* __restrict__ Wt1,
                                              const ushort_t* __restrict__ A2,
                                              const ushort_t* __restrict__ Wt2,
                                              ushort_t* __restrict__ Cb, int M,
                                              const float* __restrict__ bias, int relu, int bx)
{
    const int K = 128;
    const int tid = threadIdx.x;
    const int m0 = bx * 64;
    const int lane = tid & 63;
    const int wv = tid >> 6;
    const int q = lane >> 4;
    const int l16 = lane & 15;
    const int sar = tid >> 2;
    const int sak = (tid & 3) << 3;
    const int sbn = tid >> 1;
    const int sbk = (tid & 1) << 4;
    const bool arow_ok = (m0 + sar) < M;

    f32x4 acc[8];
#pragma unroll
    for (int t = 0; t < 8; t++) acc[t] = (f32x4){0.f, 0.f, 0.f, 0.f};

    for (int ph = 0; ph < 2; ph++) {
        const ushort_t* Arow = (ph ? A2 : A1) + (size_t)(m0 + sar) * K;
        const ushort_t* Wrow = (ph ? Wt2 : Wt1) + (size_t)sbn * K;
        for (int k0 = 0; k0 < K; k0 += 32) {
            uint4 apk = arow_ok ? *(const uint4*)(Arow + k0 + sak) : make_uint4(0, 0, 0, 0);
            uint4 b0 = *(const uint4*)(Wrow + k0 + sbk);
            uint4 b1 = *(const uint4*)(Wrow + k0 + sbk + 8);
            __syncthreads();
            *(uint4*)&As[sar][sak] = apk;
            *(uint4*)&Bs[sbn][sbk] = b0;
            *(uint4*)&Bs[sbn][sbk + 8] = b1;
            __syncthreads();
            bf16x8 af = *(const bf16x8*)&As[16 * wv + l16][q * 8];
#pragma unroll
            for (int t = 0; t < 8; t++) {
                bf16x8 bf = *(const bf16x8*)&Bs[t * 16 + l16][q * 8];
                acc[t] = __builtin_amdgcn_mfma_f32_16x16x32_bf16(af, bf, acc[t], 0, 0, 0);
            }
        }
    }
#pragma unroll
    for (int t = 0; t < 8; t++) {
        int col = t * 16 + l16;
        float bb = bias ? bias[col] : 0.f;
#pragma unroll
        for (int r = 0; r < 4; r++) {
            int row = m0 + 16 * wv + q * 4 + r;
            float val = acc[t][r] + bb;
            if (relu) val = fmaxf(val, 0.f);
            float other = __shfl_xor(val, 1);
            if (!(lane & 1) && row < M) {
                unsigned int pk = f2bu(val) | (f2bu(other) << 16);
                *(unsigned int*)(Cb + (size_t)row * 128 + col) = pk;
            }
        }
    }
}

// ---------- device: no-LDS wave-tile GEMM (K=128, col-split 4) ----------
__device__ __forceinline__ void gemm_wv_dev(const ushort_t* __restrict__ A,
                                            const ushort_t* __restrict__ Wt,
                                            ushort_t* __restrict__ Cb, int M,
                                            const float* __restrict__ bias, int relu,
                                            int w, int lane)
{
    const int K = 128;
    int ct = w & 3;
    int rt = w >> 2;
    int row0 = rt * 16;
    if (row0 >= M) return;
    int l16 = lane & 15, q = lane >> 4;
    int arow = row0 + l16;
    bool aok = arow < M;
    const ushort_t* Ar = A + (size_t)arow * K + q * 8;
    const ushort_t* W0 = Wt + (size_t)(ct * 32 + l16) * K + q * 8;
    const ushort_t* W1 = W0 + (size_t)16 * K;
    bf16x8 zz = {0, 0, 0, 0, 0, 0, 0, 0};
    f32x4 a0 = {0.f, 0.f, 0.f, 0.f}, a1 = {0.f, 0.f, 0.f, 0.f};
#pragma unroll
    for (int k0 = 0; k0 < K; k0 += 32) {
        bf16x8 af = aok ? *(const bf16x8*)(Ar + k0) : zz;
        bf16x8 b0 = *(const bf16x8*)(W0 + k0);
        bf16x8 b1 = *(const bf16x8*)(W1 + k0);
        a0 = __builtin_amdgcn_mfma_f32_16x16x32_bf16(af, b0, a0, 0, 0, 0);
        a1 = __builtin_amdgcn_mfma_f32_16x16x32_bf16(af, b1, a1, 0, 0, 0);
    }
    f32x4 av[2] = {a0, a1};
#pragma unroll
    for (int t = 0; t < 2; t++) {
        int col = ct * 32 + t * 16 + l16;
        float bb = bias ? bias[col] : 0.f;
#pragma unroll
        for (int r = 0; r < 4; r++) {
            int row = row0 + q * 4 + r;
            float val = av[t][r] + bb;
            if (relu) val = fmaxf(val, 0.f);
            float other = __shfl_xor(val, 1);
            if (!(l16 & 1) && row < M) {
                unsigned int pk = f2bu(val) | (f2bu(other) << 16);
                *(unsigned int*)(Cb + (size_t)row * 128 + col) = pk;
            }
        }
    }
}

// ---------- device: dual gather layer-1 (software-pipelined rows) ----------
__device__ __forceinline__ void gather2_dev(const ushort_t* __restrict__ Xb,
                                            ushort_t* __restrict__ OutA, ushort_t* __restrict__ OutB,
                                            const int* __restrict__ rowptr, const int* __restrict__ csr,
                                            const float* __restrict__ ecA, const float* __restrict__ ecB,
                                            const float* __restrict__ dinvl, int M, int bx)
{
    int node = bx * 4 + (threadIdx.x >> 6);
    int lane = threadIdx.x & 63;
    if (node >= M) return;
    int beg = rowptr[node], end = rowptr[node + 1];
    int slot = lane >> 4, g = lane & 15;
    float aA[8] = {0, 0, 0, 0, 0, 0, 0, 0};
    float aB[8] = {0, 0, 0, 0, 0, 0, 0, 0};

    float cAa = 0.f, cBa = 0.f, cAb = 0.f, cBb = 0.f;
    int na = 0, nb = 0;
    float nAa = 0.f, nBa = 0.f, nAb = 0.f, nBb = 0.f;
    uint4 xA, xB;
    {
        int r0 = beg + slot, r1 = beg + 4 + slot;
        int ia = 0, ib = 0;
        if (r0 < end) { ia = csr[r0]; cAa = ecA[r0]; cBa = ecB[r0]; }
        if (r1 < end) { ib = csr[r1]; cAb = ecA[r1]; cBb = ecB[r1]; }
        xA = *(const uint4*)(Xb + (size_t)ia * 128 + g * 8);
        xB = *(const uint4*)(Xb + (size_t)ib * 128 + g * 8);
    }
    {
        int r0 = beg + 8 + slot, r1 = beg + 12 + slot;
        if (r0 < end) { na = csr[r0]; nAa = ecA[r0]; nBa = ecB[r0]; }
        if (r1 < end) { nb = csr[r1]; nAb = ecA[r1]; nBb = ecB[r1]; }
    }
    for (int e = beg; e < end; e += 8) {
        uint4 xA2 = *(const uint4*)(Xb + (size_t)na * 128 + g * 8);
        uint4 xB2 = *(const uint4*)(Xb + (size_t)nb * 128 + g * 8);
        int r0 = e + 16 + slot, r1 = e + 20 + slot;
        int ma = 0, mb = 0;
        float mAa = 0.f, mBa = 0.f, mAb = 0.f, mBb = 0.f;
        if (r0 < end) { ma = csr[r0]; mAa = ecA[r0]; mBa = ecB[r0]; }
        if (r1 < end) { mb = csr[r1]; mAb = ecA[r1]; mBb = ecB[r1]; }
        fma8(xA, cAa, aA); fma8(xA, cBa, aB);
        fma8(xB, cAb, aA); fma8(xB, cBb, aB);
        xA = xA2; xB = xB2;
        cAa = nAa; cBa = nBa; cAb = nAb; cBb = nBb;
        na = ma; nb = mb;
        nAa = mAa; nBa = mBa; nAb = mAb; nBb = mBb;
    }
#pragma unroll
    for (int j = 0; j < 8; j++) {
        aA[j] += __shfl_xor(aA[j], 16); aA[j] += __shfl_xor(aA[j], 32);
        aB[j] += __shfl_xor(aB[j], 16); aB[j] += __shfl_xor(aB[j], 32);
    }
    {
        float c = dinvl[node]; c *= c;
        uint4 xs = *(const uint4*)(Xb + (size_t)node * 128 + g * 8);
        fma8(xs, c, aB);
    }
    if (lane < 16) {
        float oA[8], oB[8];
#pragma unroll
        for (int j = 0; j < 8; j++) { oA[j] = -aA[j]; oB[j] = aB[j]; }
        size_t ofs = (size_t)node * 128 + g * 8;
        *(uint4*)(OutA + ofs) = pack8(oA);
        *(uint4*)(OutB + ofs) = pack8(oB);
    }
}

// ---------- device: dual-input gather layer-2 (software-pipelined rows) ----------
__device__ __forceinline__ void gather_l2_dev(const ushort_t* __restrict__ XA,
                                              const ushort_t* __restrict__ XB,
                                              ushort_t* __restrict__ OutA, ushort_t* __restrict__ OutB,
                                              const int* __restrict__ rowptr, const int* __restrict__ csr,
                                              const float* __restrict__ ecA, const float* __restrict__ ecB,
                                              const float* __restrict__ dinvl, int M, int bx)
{
    int node = bx * 4 + (threadIdx.x >> 6);
    int lane = threadIdx.x & 63;
    if (node >= M) return;
    int beg = rowptr[node], end = rowptr[node + 1];
    int slot = lane >> 4, g = lane & 15;
    float aA[8] = {0, 0, 0, 0, 0, 0, 0, 0};
    float aB[8] = {0, 0, 0, 0, 0, 0, 0, 0};

    float cAa = 0.f, cBa = 0.f, cAb = 0.f, cBb = 0.f;
    int na = 0, nb = 0;
    float nAa = 0.f, nBa = 0.f, nAb = 0.f, nBb = 0.f;
    uint4 ra, rb, sa, sb;
    {
        int r0 = beg + slot, r1 = beg + 4 + slot;
        int ia = 0, ib = 0;
        if (r0 < end) { ia = csr[r0]; cAa = ecA[r0]; cBa = ecB[r0]; }
        if (r1 < end) { ib = csr[r1]; cAb = ecA[r1]; cBb = ecB[r1]; }
        ra = *(const uint4*)(XA + (size_t)ia * 128 + g * 8);
        rb = *(const uint4*)(XA + (size_t)ib * 128 + g * 8);
        sa = *(const uint4*)(XB + (size_t)ia * 128 + g * 8);
        sb = *(const uint4*)(XB + (size_t)ib * 128 + g * 8);
    }
    {
        int r0 = beg + 8 + slot, r1 = beg + 12 + slot;
        if (r0 < end) { na = csr[r0]; nAa = ecA[r0]; nBa = ecB[r0]; }
        if (r1 < end) { nb = csr[r1]; nAb = ecA[r1]; nBb = ecB[r1]; }
    }
    for (int e = beg; e < end; e += 8) {
        uint4 ra2 = *(const uint4*)(XA + (size_t)na * 128 + g * 8);
        uint4 rb2 = *(const uint4*)(XA + (size_t)nb * 128 + g * 8);
        uint4 sa2 = *(const uint4*)(XB + (size_t)na * 128 + g * 8);
        uint4 sb2 = *(const uint4*)(XB + (size_t)nb * 128 + g * 8);
        int r0 = e + 16 + slot, r1 = e + 20 + slot;
        int ma = 0, mb = 0;
        float mAa = 0.f, mBa = 0.f, mAb = 0.f, mBb = 0.f;
        if (r0 < end) { ma = csr[r0]; mAa = ecA[r0]; mBa = ecB[r0]; }
        if (r1 < end) { mb = csr[r1]; mAb = ecA[r1]; mBb = ecB[r1]; }
        fma8(ra, cAa, aA); fma8(rb, cAb, aA);
        fma8(sa, cBa, aB); fma8(sb, cBb, aB);
        ra = ra2; rb = rb2; sa = sa2; sb = sb2;
        cAa = nAa; cBa = nBa; cAb = nAb; cBb = nBb;
        na = ma; nb = mb;
        nAa = mAa; nBa = mBa; nAb = mAb; nBb = mBb;
    }
#pragma unroll
    for (int j = 0; j < 8; j++) {
        aA[j] += __shfl_xor(aA[j], 16); aA[j] += __shfl_xor(aA[j], 32);
        aB[j] += __shfl_xor(aB[j], 16); aB[j] += __shfl_xor(aB[j], 32);
    }
    {
        float c = dinvl[node]; c *= c;
        uint4 xs = *(const uint4*)(XB + (size_t)node * 128 + g * 8);
        fma8(xs, c, aB);
    }
    if (lane < 16) {
        float oA[8], oB[8];
#pragma unroll
        for (int j = 0; j < 8; j++) { oA[j] = -aA[j]; oB[j] = aB[j]; }
        size_t ofs = (size_t)node * 128 + g * 8;
        *(uint4*)(OutA + ofs) = pack8(oA);
        *(uint4*)(OutB + ofs) = pack8(oB);
    }
}

// ---------- device: attention with fused skip-add (+relu), software-pipelined ----------
__device__ __forceinline__ void gt_attn_dev(const ushort_t* __restrict__ Qb,
                                            const ushort_t* __restrict__ KV,
                                            const int* __restrict__ rowptr, const int* __restrict__ csr,
                                            const ushort_t* __restrict__ sk, int relu,
                                            ushort_t* __restrict__ Outb, int M, int bx)
{
    const float SCL = 0.17677669529663689f * 1.4426950408889634f;
    int node = bx * 4 + (threadIdx.x >> 6);
    int lane = threadIdx.x & 63;
    if (node >= M) return;
    int beg = rowptr[node], end = rowptr[node + 1];
    int slot = lane >> 4, g = lane & 15;
    uint4 qv = *(const uint4*)(Qb + (size_t)node * 128 + g * 8);
    float qf[8];
    unpack8(qv, qf);
#pragma unroll
    for (int j = 0; j < 8; j++) qf[j] *= SCL;
    float ax[8] = {0, 0, 0, 0, 0, 0, 0, 0};
    float den = 0.f;

    bool va = false, vb = false;
    int na = 0, nb = 0;
    bool wa = false, wb = false;
    uint4 kA, kB, uA, uB;
    {
        int r0 = beg + slot, r1 = beg + 4 + slot;
        va = r0 < end; vb = r1 < end;
        int ia = va ? csr[r0] : 0;
        int ib = vb ? csr[r1] : 0;
        const ushort_t* p0 = KV + (size_t)ia * 256 + g * 8;
        const ushort_t* p1 = KV + (size_t)ib * 256 + g * 8;
        kA = *(const uint4*)p0; uA = *(const uint4*)(p0 + 128);
        kB = *(const uint4*)p1; uB = *(const uint4*)(p1 + 128);
    }
    {
        int r0 = beg + 8 + slot, r1 = beg + 12 + slot;
        wa = r0 < end; wb = r1 < end;
        na = wa ? csr[r0] : 0;
        nb = wb ? csr[r1] : 0;
    }
    for (int e = beg; e < end; e += 8) {
        const ushort_t* p0 = KV + (size_t)na * 256 + g * 8;
        const ushort_t* p1 = KV + (size_t)nb * 256 + g * 8;
        uint4 kA2 = *(const uint4*)p0;
        uint4 uA2 = *(const uint4*)(p0 + 128);
        uint4 kB2 = *(const uint4*)p1;
        uint4 uB2 = *(const uint4*)(p1 + 128);
        int r0 = e + 16 + slot, r1 = e + 20 + slot;
        bool xa = r0 < end, xb = r1 < end;
        int ma = xa ? csr[r0] : 0;
        int mb = xb ? csr[r1] : 0;
        float d0 = dot8(kA, qf);
        float d1 = dot8(kB, qf);
        d0 += __shfl_xor(d0, 1); d0 += __shfl_xor(d0, 2);
        d1 += __shfl_xor(d1, 1); d1 += __shfl_xor(d1, 2);
        float w0 = va ? exp2f(fminf(d0, 80.f)) : 0.f;
        float w1 = vb ? exp2f(fminf(d1, 80.f)) : 0.f;
        den += w0 + w1;
        fma8(uA, w0, ax);
        fma8(uB, w1, ax);
        kA = kA2; kB = kB2; uA = uA2; uB = uB2;
        va = wa; vb = wb;
        wa = xa; wb = xb; na = ma; nb = mb;
    }
#pragma unroll
    for (int j = 0; j < 8; j++) {
        ax[j] += __shfl_xor(ax[j], 16); ax[j] += __shfl_xor(ax[j], 32);
    }
    den += __shfl_xor(den, 16); den += __shfl_xor(den, 32);
    float dd = fmaxf(den, 1e-9f);
    if (lane < 16) {
        uint4 sv = *(const uint4*)(sk + (size_t)node * 128 + g * 8);
        float sf[8];
        unpack8(sv, sf);
        float o[8];
#pragma unroll
        for (int j = 0; j < 8; j++) {
            float v = ax[j] / dd + sf[j];
            o[j] = relu ? fmaxf(v, 0.f) : v;
        }
        *(uint4*)(Outb + (size_t)node * 128 + g * 8) = pack8(o);
    }
}

// ---------- merged: gather2 + MLP-L1 + QKVS1 panels (all read hb) ----------
__global__ __launch_bounds__(256)
void flatA_kernel(const ushort_t* __restrict__ hb,
                  ushort_t* __restrict__ x1, ushort_t* __restrict__ x2,
                  const int* __restrict__ rowptr, const int* __restrict__ csr,
                  const float* __restrict__ ecA, const float* __restrict__ ecB,
                  const float* __restrict__ dinvl, int N,
                  const ushort_t* __restrict__ wmlp1, ushort_t* __restrict__ xm,
                  const float* __restrict__ b18,
                  const ushort_t* __restrict__ wqkvs,
                  ushort_t* __restrict__ qb, ushort_t* __restrict__ kvb,
                  ushort_t* __restrict__ skb,
                  const float* __restrict__ bq, const float* __restrict__ bk,
                  const float* __restrict__ bv, const float* __restrict__ bs)
{
    __shared__ ushort_t As[64][40];
    __shared__ ushort_t Bs[128][40];
    int bx = blockIdx.x;
    int gN4 = (N + 3) >> 2;
    int RT = (N + 15) >> 4;
    int gG = (N + 63) >> 6;
    const size_t PS = (size_t)128 * 128;
    if (bx < gN4) {
        gather2_dev(hb, x1, x2, rowptr, csr, ecA, ecB, dinvl, N, bx);
    } else if (bx < gN4 + RT) {
        int w = (bx - gN4) * 4 + (threadIdx.x >> 6);
        gemm_wv_dev(hb, wmlp1, xm, N, b18, 1, w, threadIdx.x & 63);
    } else {
        int b2 = bx - gN4 - RT;
        int pan = b2 / gG;
        int gx = b2 - pan * gG;
        if (pan == 0) gemm_bfs_dev(As, Bs, hb, wqkvs, qb, 128, N, bq, gx);
        else if (pan == 1) gemm_bfs_dev(As, Bs, hb, wqkvs + PS, kvb, 256, N, bk, gx);
        else if (pan == 2) gemm_bfs_dev(As, Bs, hb, wqkvs + 2 * PS, kvb + 128, 256, N, bv, gx);
        else gemm_bfs_dev(As, Bs, hb, wqkvs + 3 * PS, skb, 128, N, bs, gx);
    }
}

// ---------- merged LDS GEMMs A: Cheb dual1 + GCN1 ----------
__global__ __launch_bounds__(256)
void megaA_kernel(const ushort_t* __restrict__ hb,
                  const ushort_t* __restrict__ wch0,
                  const ushort_t* __restrict__ x1, const ushort_t* __restrict__ wch1,
                  ushort_t* __restrict__ x0, const float* __restrict__ bch,
                  const ushort_t* __restrict__ x2, const ushort_t* __restrict__ wgcn,
                  ushort_t* __restrict__ xg1, const float* __restrict__ bgcn,
                  int M)
{
    __shared__ ushort_t As[64][40];
    __shared__ ushort_t Bs[128][40];
    if (blockIdx.y == 0)
        gemm_dual_dev(As, Bs, hb, wch0, x1, wch1, x0, M, bch, 1, blockIdx.x);
    else
        gemm_bf_dev<128>(As, Bs, x2, wgcn, xg1, M, bgcn, 1, blockIdx.x);
}

// ---------- merged: attn1 + gather_l2 + MLP-L2 (no LDS) ----------
__global__ void flatB_kernel(const ushort_t* __restrict__ qb, const ushort_t* __restrict__ kvb,
                             const int* __restrict__ rowptr, const int* __restrict__ csr,
                             const ushort_t* __restrict__ skb, ushort_t* __restrict__ aout,
                             const ushort_t* __restrict__ x0, const ushort_t* __restrict__ xg1,
                             ushort_t* __restrict__ x3, ushort_t* __restrict__ x2,
                             const float* __restrict__ ecA, const float* __restrict__ ecB,
                             const float* __restrict__ dinvl, int N,
                             const ushort_t* __restrict__ xm, const ushort_t* __restrict__ wmlp2,
                             ushort_t* __restrict__ e0b, const float* __restrict__ bmlp2)
{
    int bx = blockIdx.x;
    int gN4 = (N + 3) >> 2;
    if (bx < gN4) gt_attn_dev(qb, kvb, rowptr, csr, skb, 1, aout, N, bx);
    else if (bx < 2 * gN4) gather_l2_dev(x0, xg1, x3, x2, rowptr, csr, ecA, ecB, dinvl, N, bx - gN4);
    else {
        int w = (bx - 2 * gN4) * 4 + (threadIdx.x >> 6);
        gemm_wv_dev(xm, wmlp2, e0b, N, bmlp2, 0, w, threadIdx.x & 63);
    }
}

// ---------- merged LDS GEMMs B: Q,K,V,S panels + Cheb dual2 + GCN2 ----------
__global__ __launch_bounds__(256)
void megaB_kernel(const ushort_t* __restrict__ x1,
                  const ushort_t* __restrict__ wqkvs,
                  ushort_t* __restrict__ qb, ushort_t* __restrict__ kvb, ushort_t* __restrict__ skb,
                  const float* __restrict__ bq, const float* __restrict__ bk,
                  const float* __restrict__ bv, const float* __restrict__ bs,
                  const ushort_t* __restrict__ x0, const ushort_t* __restrict__ wch0,
                  const ushort_t* __restrict__ x3, const ushort_t* __restrict__ wch1,
                  ushort_t* __restrict__ e1b, const float* __restrict__ bch,
                  const ushort_t* __restrict__ x2, const ushort_t* __restrict__ wgcn,
                  ushort_t* __restrict__ e3b, const float* __restrict__ bgcn,
                  int M)
{
    __shared__ ushort_t As[64][40];
    __shared__ ushort_t Bs[128][40];
    int y = blockIdx.y, bx = blockIdx.x;
    const size_t PS = (size_t)128 * 128;
    if (y == 0) gemm_bfs_dev(As, Bs, x1, wqkvs, qb, 128, M, bq, bx);
    else if (y == 1) gemm_bfs_dev(As, Bs, x1, wqkvs + PS, kvb, 256, M, bk, bx);
    else if (y == 2) gemm_bfs_dev(As, Bs, x1, wqkvs + 2 * PS, kvb + 128, 256, M, bv, bx);
    else if (y == 3) gemm_bfs_dev(As, Bs, x1, wqkvs + 3 * PS, skb, 128, M, bs, bx);
    else if (y == 4) gemm_dual_dev(As, Bs, x0, wch0, x3, wch1, e1b, M, bch, 0, bx);
    else gemm_bf_dev<128>(As, Bs, x2, wgcn, e3b, M, bgcn, 0, bx);
}

// ---------- merged: attn2 + poolA (h, e0, e1, e3) ----------
__global__ void attn2_pool_kernel(const ushort_t* __restrict__ Qb, const ushort_t* __restrict__ KV,
                                  const int* __restrict__ rowptr, const int* __restrict__ csr,
                                  const ushort_t* __restrict__ sk, ushort_t* __restrict__ e2b,
                                  int N,
                                  const ushort_t* __restrict__ hb,
                                  const ushort_t* __restrict__ e0, const ushort_t* __restrict__ e1,
                                  const ushort_t* __restrict__ e3,
                                  const float* __restrict__ gates,
                                  const float* __restrict__ png, const float* __restrict__ pnb,
                                  const float* __restrict__ esc,
                                  const int* __restrict__ bstart, const int* __restrict__ bend,
                                  float* __restrict__ partial)
{
    int bx = blockIdx.x;
    int gN4 = (N + 3) >> 2;
    if (bx < gN4) {
        gt_attn_dev(Qb, KV, rowptr, csr, sk, 0, e2b, N, bx);
        return;
    }
    int idx = bx - gN4;              // 0 .. B*PCH/4-1
    int b = idx >> 3;                // PCH/4 == 8
    int cq = ((idx & 7) << 2) + (threadIdx.x >> 6);
    int lane = threadIdx.x & 63;
    int s0 = bstart[b], eN = bend[b];
    const ushort_t* eps[3] = {e0, e1, e3};
    const int eid[3] = {0, 1, 3};
    float ga[3], gb[3], ba[3], bb[3], es[3];
#pragma unroll
    for (int j = 0; j < 3; j++) {
        int ee = eid[j];
        ga[j] = png[ee * 128 + lane * 2];
        gb[j] = png[ee * 128 + lane * 2 + 1];
        ba[j] = pnb[ee * 128 + lane * 2];
        bb[j] = pnb[ee * 128 + lane * 2 + 1];
        es[j] = esc[ee];
    }
    float sx = 0.f, sy = 0.f;
    for (int n = s0 + cq; n < eN; n += PCH) {
        size_t ofs = (size_t)n * 128 + lane * 2;
        float4 gg = *(const float4*)(gates + (size_t)n * 4);
        float gv[3] = {gg.x, gg.y, gg.w};
        unsigned int hu = *(const unsigned int*)(hb + ofs);
        float ox = bf2f(hu & 0xffff), oy = bf2f(hu >> 16);
#pragma unroll
        for (int j = 0; j < 3; j++) {
            unsigned int u = *(const unsigned int*)(eps[j] + ofs);
            float vx = bf2f(u & 0xffff), vy = bf2f(u >> 16);
            float su = vx + vy, sq = vx * vx + vy * vy;
#pragma unroll
            for (int off = 32; off; off >>= 1) { su += __shfl_xor(su, off); sq += __shfl_xor(sq, off); }
            float mean = su * (1.f / 128.f);
            float var = sq * (1.f / 128.f) - mean * mean;
            float inv = rsqrtf(var + 1e-5f);
            float cc = es[j] * gv[j];
            ox = fmaf(cc, (vx - mean) * inv * ga[j] + ba[j], ox);
            oy = fmaf(cc, (vy - mean) * inv * gb[j] + bb[j], oy);
        }
        sx += ox; sy += oy;
    }
    *(float2*)(partial + ((size_t)b * PCH + cq) * 128 + lane * 2) = make_float2(sx, sy);
}

// ---------- poolB: expert 2 contribution -> partial2 ----------
__global__ void poolB_kernel(const ushort_t* __restrict__ e2,
                             const float* __restrict__ gates,
                             const float* __restrict__ png, const float* __restrict__ pnb,
                             const float* __restrict__ esc,
                             const int* __restrict__ bstart, const int* __restrict__ bend,
                             float* __restrict__ partial2)
{
    int idx = blockIdx.x;
    int b = idx >> 3;
    int cq = ((idx & 7) << 2) + (threadIdx.x >> 6);
    int lane = threadIdx.x & 63;
    int s0 = bstart[b], eN = bend[b];
    float ga = png[2 * 128 + lane * 2], gb = png[2 * 128 + lane * 2 + 1];
    float ba = pnb[2 * 128 + lane * 2], bb = pnb[2 * 128 + lane * 2 + 1];
    float es = esc[2];
    float sx = 0.f, sy = 0.f;
    for (int n = s0 + cq; n < eN; n += PCH) {
        size_t ofs = (size_t)n * 128 + lane * 2;
        float gv = gates[(size_t)n * 4 + 2];
        unsigned int u = *(const unsigned int*)(e2 + ofs);
        float vx = bf2f(u & 0xffff), vy = bf2f(u >> 16);
        float su = vx + vy, sq = vx * vx + vy * vy;
#pragma unroll
        for (int off = 32; off; off >>= 1) { su += __shfl_xor(su, off); sq += __shfl_xor(sq, off); }
        float mean = su * (1.f / 128.f);
        float var = sq * (1.f / 128.f) - mean * mean;
        float inv = rsqrtf(var + 1e-5f);
        float cc = es * gv;
        sx = fmaf(cc, (vx - mean) * inv * ga + ba, sx);
        sy = fmaf(cc, (vy - mean) * inv * gb + bb, sy);
    }
    *(float2*)(partial2 + ((size_t)b * PCH + cq) * 128 + lane * 2) = make_float2(sx, sy);
}

// ---------- classification head (with fused pool reduce over partial+partial2) ----------
__global__ void head_kernel(const float* __restrict__ partial,
                            const float* __restrict__ partial2,
                            const int* __restrict__ bstart, const int* __restrict__ bend,
                            const float* __restrict__ h1W, const float* __restrict__ h1b,
                            const float* __restrict__ h1g, const float* __restrict__ h1be,
                            const float* __restrict__ h2W, const float* __restrict__ h2b,
                            const float* __restrict__ h2g, const float* __restrict__ h2be,
                            const float* __restrict__ h3W, const float* __restrict__ h3b,
                            const float* __restrict__ lbias,
                            float* __restrict__ out, int B)
{
    __shared__ float p[128], z[128];
    int b = blockIdx.x, t = threadIdx.x;
    float sum = 0.f;
#pragma unroll
    for (int c = 0; c < PCH; c++) {
        size_t o = ((size_t)b * PCH + c) * 128 + t;
        sum += partial[o] + partial2[o];
    }
    float cnt = fmaxf((float)(bend[b] - bstart[b]), 1.f);
    p[t] = sum / cnt;
    __syncthreads();
    float a = h1b[t];
    for (int k = 0; k < 128; k++) a = fmaf(p[k], h1W[k * 128 + t], a);
    z[t] = a;
    __syncthreads();
    float s = 0.f, sq = 0.f;
    for (int k = 0; k < 128; k++) { float x = z[k]; s += x; sq += x * x; }
    float mean = s * (1.f / 128.f), var = sq * (1.f / 128.f) - mean * mean;
    float y = fmaxf((a - mean) * rsqrtf(var + 1e-5f) * h1g[t] + h1be[t], 0.f);
    __syncthreads();
    z[t] = y;
    __syncthreads();
    float a2 = 0.f;
    if (t < 64) {
        a2 = h2b[t];
        for (int k = 0; k < 128; k++) a2 = fmaf(z[k], h2W[k * 64 + t], a2);
    }
    __syncthreads();
    if (t < 64) p[t] = a2;
    __syncthreads();
    if (t < 2) {
        float s2 = 0.f, sq2 = 0.f;
        for (int k = 0; k < 64; k++) { float x = p[k]; s2 += x; sq2 += x * x; }
        float mean2 = s2 * (1.f / 64.f), var2 = sq2 * (1.f / 64.f) - mean2 * mean2;
        float inv2 = rsqrtf(var2 + 1e-5f);
        float o = h3b[t] + lbias[t];
        for (int k = 0; k < 64; k++) {
            float zc = fmaxf((p[k] - mean2) * inv2 * h2g[k] + h2be[k], 0.f);
            o = fmaf(zc, h3W[k * 2 + t], o);
        }
        out[b * 2 + t] = o;
    }
}

// ---------------- launch ----------------
extern "C" void kernel_launch(void* const* d_in, const int* in_sizes, int n_in,
                              void* d_out, int out_size, void* d_ws, size_t ws_size,
                              hipStream_t stream)
{
    (void)ws_size; (void)n_in;
    const int N = in_sizes[3];
    const int E = in_sizes[2] / 2;
    const int B = out_size / 2;

    const int* ei = (const int*)d_in[2];
    const int* src = ei;
    const int* dst = ei + E;
    const int* batch = (const int*)d_in[3];

    const float* W[47];
    for (int i = 0; i < 47; i++) W[i] = (const float*)d_in[i];

    size_t fN = (size_t)N;
    float* gates    = (float*)d_ws;                    // 4N
    float* dinv     = gates + 4 * fN;                  // N
    float* dinvl    = dinv + fN;                       // N
    float* partial  = dinvl + fN;                      // 128*B*PCH
    float* partial2 = partial + (size_t)128 * B * PCH; // 128*B*PCH
    float* logitsA  = partial2 + (size_t)128 * B * PCH;
    float* logitsB  = logitsA + 4 * fN;
    ushort_t* hb  = (ushort_t*)(logitsB + 4 * fN);
    ushort_t* e0b = hb + 128 * fN;
    ushort_t* e1b = e0b + 128 * fN;
    ushort_t* e2b = e1b + 128 * fN;
    ushort_t* e3b = e2b + 128 * fN;
    ushort_t* x0  = e3b + 128 * fN;
    ushort_t* x1  = x0 + 128 * fN;
    ushort_t* x2  = x1 + 128 * fN;
    ushort_t* x3  = x2 + 128 * fN;
    ushort_t* xm  = x3 + 128 * fN;
    ushort_t* xg1 = xm + 128 * fN;
    ushort_t* skb = xg1 + 128 * fN;
    ushort_t* qb  = skb + 128 * fN;
    ushort_t* kvb = qb + 128 * fN;           // 256N
    ushort_t* hrb = kvb + 256 * fN;          // 256N bf16 (router features)
    ushort_t* wt  = hrb + 256 * fN;
    WtPack wp;
    const float* wsrc[NWT] = {
        W[4], W[8], W[12], W[17], W[19],
        W[21], W[21] + 16384, W[21] + 32768, W[21] + 49152,
        W[23], W[25], W[27], W[29],                                     // q1,k1,v1,s1 (contiguous 512)
        W[23] + 16384, W[25] + 16384, W[27] + 16384, W[29] + 16384,     // q2,k2,v2,s2
        W[31], W[31] + 16384
    };
    const int wk[NWT] = {200, 128, 256, 128, 128,
                         128, 128, 128, 128,
                         128, 128, 128, 128,
                         128, 128, 128, 128,
                         128, 128};
    unsigned long long woff[NWT];
    unsigned long long acc_off = 0;
    for (int i = 0; i < NWT; i++) {
        wp.src[i] = wsrc[i];
        wp.K[i] = wk[i];
        wp.off[i] = acc_off;
        woff[i] = acc_off;
        acc_off += (unsigned long long)128 * wk[i];
    }
    int* degi   = (int*)(wt + acc_off + 8);
    int* cursor = degi + N;
    int* rowptr = cursor + N;
    int* csr    = rowptr + (N + 1);
    int* bstart = csr + E;
    int* bend   = bstart + B;
    int* bsum   = bend + B;
    float* ecA  = (float*)(bsum + 256);      // E floats (CSR-ordered sym-norm coefs)
    float* ecB  = ecA + E;                   // E floats (CSR-ordered GCN coefs)

    dim3 blk(256);
    int gN4 = (N + 3) / 4;
    int gG = (N + 63) / 64;
    int RT = (N + 15) / 16;
    int nsb = (N + SCH - 1) / SCH;
    int nseg = (N + 255) / 256;
    int nedge = (E + 255) / 256;
    int npool = B * (PCH / 4);

    // zero degi+cursor and bstart+bend (stream-ordered, graph-capturable)
    hipMemsetAsync(degi, 0, (size_t)2 * N * sizeof(int), stream);
    hipMemsetAsync(bstart, 0, (size_t)2 * B * sizeof(int), stream);

    // L0: wconv + seg_bounds + edge_deg
    setup_mega_kernel<<<dim3(608 + nseg + nedge), blk, 0, stream>>>(
        wp, wt, batch, bstart, bend, N, dst, degi, E);
    // L1/L2: scan phases
    scan1_kernel<<<dim3(nsb), blk, 0, stream>>>(degi, rowptr, bsum, N);
    scan2_kernel<<<1, blk, 0, stream>>>(bsum, nsb);
    // L3: scan3 + both encoder GEMMs (independent)
    EncCfg c0 = {W[0], 200, 200, wt + woff[0], hrb, W[5], W[6], W[7], W[16], logitsA};
    EncCfg c1 = {W[1], 128, 128, wt + woff[1], hrb + 128, W[9], W[10], W[11], W[16] + 512, logitsB};
    scan3_enc_kernel<<<dim3(nseg + 2 * gG), blk, 0, stream>>>(
        rowptr, bsum, degi, dinv, dinvl, N, c0, c1);
    // L4: fuse GEMM (K=256)+LN+ReLU -> hb  ||  csr_fill  ||  router top-k
    ln_csr_topk_kernel<<<dim3(gG + nedge + nseg), blk, 0, stream>>>(
        hrb, wt + woff[2], hb, N, W[13], W[14], W[15],
        src, dst, rowptr, cursor, csr, dinv, dinvl, ecA, ecB, E,
        logitsA, logitsB, gates);
    // L5: gather2 + MLP-L1 + QKVS1 panels (all read hb)
    flatA_kernel<<<dim3(gN4 + RT + 4 * gG), blk, 0, stream>>>(
        hb, x1, x2, rowptr, csr, ecA, ecB, dinvl, N,
        wt + woff[3], xm, W[18],
        wt + woff[9], qb, kvb, skb, W[24], W[26], W[28], W[30]);
    // L6: Cheb dual1 + GCN1
    megaA_kernel<<<dim3(gG, 2), blk, 0, stream>>>(
        hb, wt + woff[5], x1, wt + woff[6], x0, W[22],
        x2, wt + woff[17], xg1, W[32], N);
    // L7: attn1 + gather_l2 + MLP-L2
    flatB_kernel<<<dim3(2 * gN4 + RT), blk, 0, stream>>>(
        qb, kvb, rowptr, csr, skb, x1,
        x0, xg1, x3, x2, ecA, ecB, dinvl, N,
        xm, wt + woff[4], e0b, W[20]);
    // L8: QKVS2 panels + Cheb dual2 + GCN2
    megaB_kernel<<<dim3(gG, 6), blk, 0, stream>>>(
        x1, wt + woff[13], qb, kvb, skb,
        W[24] + 128, W[26] + 128, W[28] + 128, W[30] + 128,
        x0, wt + woff[7], x3, wt + woff[8], e1b, W[22] + 128,
        x2, wt + woff[18], e3b, W[32] + 128, N);
    // L9: attn2 -> e2b  ||  poolA (h, e0, e1, e3)
    attn2_pool_kernel<<<dim3(gN4 + npool), blk, 0, stream>>>(
        qb, kvb, rowptr, csr, skb, e2b, N,
        hb, e0b, e1b, e3b, gates, W[33], W[34], W[35], bstart, bend, partial);
    // L10: poolB (e2) -> partial2
    poolB_kernel<<<dim3(npool), blk, 0, stream>>>(
        e2b, gates, W[33], W[34], W[35], bstart, bend, partial2);
    // L11: head
    head_kernel<<<dim3(B), dim3(128), 0, stream>>>(partial, partial2, bstart, bend,
        W[36], W[37], W[38], W[39],
        W[40], W[41], W[42], W[43],
        W[44], W[45], W[46],
        (float*)d_out, B);
}

// Round 10
// 498.148 us; speedup vs baseline: 1.0388x; 1.0388x over previous
//
#include <hip/hip_runtime.h>

#define PCH   32
#define NWT   19
#define SCH   2048

typedef unsigned short ushort_t;
typedef __attribute__((ext_vector_type(8))) short bf16x8;
typedef __attribute__((ext_vector_type(4))) float f32x4;

__device__ __forceinline__ float bf2f(unsigned int v) {
    return __uint_as_float(v << 16);
}
__device__ __forceinline__ unsigned int f2bu(float f) {
    unsigned int u = __float_as_uint(f);
    return (u + 0x7fffu + ((u >> 16) & 1u)) >> 16;
}
__device__ __forceinline__ void unpack8(uint4 u, float* f) {
    f[0] = bf2f(u.x & 0xffff); f[1] = bf2f(u.x >> 16);
    f[2] = bf2f(u.y & 0xffff); f[3] = bf2f(u.y >> 16);
    f[4] = bf2f(u.z & 0xffff); f[5] = bf2f(u.z >> 16);
    f[6] = bf2f(u.w & 0xffff); f[7] = bf2f(u.w >> 16);
}
__device__ __forceinline__ uint4 pack8(const float* f) {
    uint4 p;
    p.x = f2bu(f[0]) | (f2bu(f[1]) << 16);
    p.y = f2bu(f[2]) | (f2bu(f[3]) << 16);
    p.z = f2bu(f[4]) | (f2bu(f[5]) << 16);
    p.w = f2bu(f[6]) | (f2bu(f[7]) << 16);
    return p;
}
__device__ __forceinline__ void fma8(uint4 u, float c, float* a) {
    a[0] = fmaf(c, bf2f(u.x & 0xffff), a[0]);
    a[1] = fmaf(c, bf2f(u.x >> 16), a[1]);
    a[2] = fmaf(c, bf2f(u.y & 0xffff), a[2]);
    a[3] = fmaf(c, bf2f(u.y >> 16), a[3]);
    a[4] = fmaf(c, bf2f(u.z & 0xffff), a[4]);
    a[5] = fmaf(c, bf2f(u.z >> 16), a[5]);
    a[6] = fmaf(c, bf2f(u.w & 0xffff), a[6]);
    a[7] = fmaf(c, bf2f(u.w >> 16), a[7]);
}
__device__ __forceinline__ float dot8(uint4 u, const float* q) {
    float d = q[0] * bf2f(u.x & 0xffff);
    d = fmaf(q[1], bf2f(u.x >> 16), d);
    d = fmaf(q[2], bf2f(u.y & 0xffff), d);
    d = fmaf(q[3], bf2f(u.y >> 16), d);
    d = fmaf(q[4], bf2f(u.z & 0xffff), d);
    d = fmaf(q[5], bf2f(u.z >> 16), d);
    d = fmaf(q[6], bf2f(u.w & 0xffff), d);
    d = fmaf(q[7], bf2f(u.w >> 16), d);
    return d;
}

struct WtPack {
    const float* src[NWT];
    unsigned long long off[NWT];
    int K[NWT];
};

// ---------------- merged setup: wconv + seg_bounds + edge_deg ----------------
__global__ void setup_mega_kernel(WtPack p, ushort_t* __restrict__ base,
                                  const int* __restrict__ batch,
                                  int* __restrict__ bstart, int* __restrict__ bend, int N,
                                  const int* __restrict__ dst, int* __restrict__ degi, int E)
{
    int bx = blockIdx.x, tid = threadIdx.x;
    int nseg = (N + 255) >> 8;
    if (bx < 608) {
        int a = bx >> 5, xp = bx & 31;
        const float* s = p.src[a];
        ushort_t* d = base + p.off[a];
        int K = p.K[a];
        int total = K * 128;
        for (int i = xp * 256 + tid; i < total; i += 32 * 256) {
            int k = i >> 7, n = i & 127;
            d[n * K + k] = (ushort_t)f2bu(s[i]);
        }
    } else if (bx < 608 + nseg) {
        int n = (bx - 608) * 256 + tid;
        if (n >= N) return;
        int b = batch[n];
        if (n == 0) bstart[b] = 0;
        else {
            int pb = batch[n - 1];
            if (pb != b) { bstart[b] = n; bend[pb] = n; }
        }
        if (n == N - 1) bend[b] = N;
    } else {
        int e = (bx - 608 - nseg) * 256 + tid;
        if (e < E) atomicAdd(&degi[dst[e]], 1);
    }
}

// ---------- parallel 3-phase scan ----------
__global__ void scan1_kernel(const int* __restrict__ degi, int* __restrict__ rowptr,
                             int* __restrict__ bsum, int n) {
    __shared__ int sh[256];
    int tid = threadIdx.x;
    int base = blockIdx.x * SCH + tid * 8;
    int loc[8]; int s = 0;
#pragma unroll
    for (int j = 0; j < 8; j++) {
        int idx = base + j;
        int v = (idx < n) ? degi[idx] : 0;
        s += v; loc[j] = s;
    }
    sh[tid] = s;
    __syncthreads();
    for (int off = 1; off < 256; off <<= 1) {
        int t = (tid >= off) ? sh[tid - off] : 0;
        __syncthreads();
        sh[tid] += t;
        __syncthreads();
    }
    int prev = (tid > 0) ? sh[tid - 1] : 0;
#pragma unroll
    for (int j = 0; j < 8; j++) {
        int idx = base + j;
        if (idx < n) rowptr[idx + 1] = prev + loc[j];
    }
    if (tid == 255) bsum[blockIdx.x] = sh[255];
}
__global__ void scan2_kernel(int* __restrict__ bsum, int nb) {
    __shared__ int sh[256];
    int tid = threadIdx.x;
    sh[tid] = (tid < nb) ? bsum[tid] : 0;
    __syncthreads();
    for (int off = 1; off < 256; off <<= 1) {
        int t = (tid >= off) ? sh[tid - off] : 0;
        __syncthreads();
        sh[tid] += t;
        __syncthreads();
    }
    if (tid < nb) bsum[tid] = (tid > 0) ? sh[tid - 1] : 0;
}

// ---------- fp32-A MFMA GEMM + fused LN+ReLU + router partials (device) ----------
struct EncCfg {
    const float* A; int lda; int K;
    const ushort_t* Wt; ushort_t* Cb;           // Cb stride 256
    const float* bias; const float* g; const float* be;
    const float* rW; float* logits;
};

__device__ __forceinline__ void gemm_f32_ln_dev(ushort_t (*As)[40], ushort_t (*Bs)[40],
                                                const EncCfg c, int bx, int M)
{
    const int tid = threadIdx.x;
    const int m0 = bx * 64;
    const int lane = tid & 63;
    const int wv = tid >> 6;
    const int q = lane >> 4;
    const int l16 = lane & 15;
    const int sar = tid >> 2;
    const int sak = (tid & 3) << 3;
    const int sbn = tid >> 1;
    const int sbk = (tid & 1) << 4;
    const int K = c.K;
    const bool arow_ok = (m0 + sar) < M;
    const float* Arow = c.A + (size_t)(m0 + sar) * c.lda;
    const ushort_t* Wrow = c.Wt + (size_t)sbn * K;

    f32x4 acc[8];
#pragma unroll
    for (int t = 0; t < 8; t++) acc[t] = (f32x4){0.f, 0.f, 0.f, 0.f};

    for (int k0 = 0; k0 < K; k0 += 32) {
        uint4 apk;
        if (arow_ok && k0 + sak + 8 <= K) {
            float4 p0 = *(const float4*)(Arow + k0 + sak);
            float4 p1 = *(const float4*)(Arow + k0 + sak + 4);
            apk.x = f2bu(p0.x) | (f2bu(p0.y) << 16);
            apk.y = f2bu(p0.z) | (f2bu(p0.w) << 16);
            apk.z = f2bu(p1.x) | (f2bu(p1.y) << 16);
            apk.w = f2bu(p1.z) | (f2bu(p1.w) << 16);
        } else {
            unsigned int t4[4] = {0, 0, 0, 0};
            for (int j = 0; j < 8; j++) {
                int k = k0 + sak + j;
                unsigned int bv = (arow_ok && k < K) ? f2bu(Arow[k]) : 0u;
                t4[j >> 1] |= bv << ((j & 1) * 16);
            }
            apk = make_uint4(t4[0], t4[1], t4[2], t4[3]);
        }
        uint4 b0, b1;
        if (k0 + sbk + 16 <= K) {
            b0 = *(const uint4*)(Wrow + k0 + sbk);
            b1 = *(const uint4*)(Wrow + k0 + sbk + 8);
        } else {
            unsigned int t8[8] = {0, 0, 0, 0, 0, 0, 0, 0};
            for (int j = 0; j < 16; j++) {
                int k = k0 + sbk + j;
                unsigned int bv = (k < K) ? (unsigned int)Wrow[k] : 0u;
                t8[j >> 1] |= bv << ((j & 1) * 16);
            }
            b0 = make_uint4(t8[0], t8[1], t8[2], t8[3]);
            b1 = make_uint4(t8[4], t8[5], t8[6], t8[7]);
        }
        __syncthreads();
        *(uint4*)&As[sar][sak] = apk;
        *(uint4*)&Bs[sbn][sbk] = b0;
        *(uint4*)&Bs[sbn][sbk + 8] = b1;
        __syncthreads();
        bf16x8 af = *(const bf16x8*)&As[16 * wv + l16][q * 8];
#pragma unroll
        for (int t = 0; t < 8; t++) {
            bf16x8 bf = *(const bf16x8*)&Bs[t * 16 + l16][q * 8];
            acc[t] = __builtin_amdgcn_mfma_f32_16x16x32_bf16(af, bf, acc[t], 0, 0, 0);
        }
    }
    const int row_base = m0 + 16 * wv + q * 4;
#pragma unroll
    for (int t = 0; t < 8; t++) {
        float bb = c.bias[t * 16 + l16];
#pragma unroll
        for (int r = 0; r < 4; r++) acc[t][r] += bb;
    }
    float mean[4], inv[4];
#pragma unroll
    for (int r = 0; r < 4; r++) {
        float s = 0.f, sq = 0.f;
#pragma unroll
        for (int t = 0; t < 8; t++) { float v = acc[t][r]; s += v; sq = fmaf(v, v, sq); }
#pragma unroll
        for (int off = 1; off <= 8; off <<= 1) { s += __shfl_xor(s, off); sq += __shfl_xor(sq, off); }
        mean[r] = s * (1.f / 128.f);
        float var = sq * (1.f / 128.f) - mean[r] * mean[r];
        inv[r] = rsqrtf(var + 1e-5f);
    }
    float rl0[4] = {0, 0, 0, 0}, rl1[4] = {0, 0, 0, 0};
    float rl2[4] = {0, 0, 0, 0}, rl3[4] = {0, 0, 0, 0};
#pragma unroll
    for (int t = 0; t < 8; t++) {
        int col = t * 16 + l16;
        float gg = c.g[col], b2 = c.be[col];
        float4 rw = *(const float4*)(c.rW + col * 4);
#pragma unroll
        for (int r = 0; r < 4; r++) {
            float y = fmaxf(fmaf((acc[t][r] - mean[r]) * inv[r], gg, b2), 0.f);
            rl0[r] = fmaf(y, rw.x, rl0[r]);
            rl1[r] = fmaf(y, rw.y, rl1[r]);
            rl2[r] = fmaf(y, rw.z, rl2[r]);
            rl3[r] = fmaf(y, rw.w, rl3[r]);
            float other = __shfl_xor(y, 1);
            int row = row_base + r;
            if (!(l16 & 1) && row < M) {
                unsigned int pk = f2bu(y) | (f2bu(other) << 16);
                *(unsigned int*)(c.Cb + (size_t)row * 256 + col) = pk;
            }
        }
    }
#pragma unroll
    for (int r = 0; r < 4; r++) {
#pragma unroll
        for (int off = 1; off <= 8; off <<= 1) {
            rl0[r] += __shfl_xor(rl0[r], off);
            rl1[r] += __shfl_xor(rl1[r], off);
            rl2[r] += __shfl_xor(rl2[r], off);
            rl3[r] += __shfl_xor(rl3[r], off);
        }
        int row = row_base + r;
        if (l16 == 0 && row < M)
            *(float4*)(c.logits + (size_t)row * 4) = make_float4(rl0[r], rl1[r], rl2[r], rl3[r]);
    }
}

// ---------- merged scan3 + encoder GEMMs ----------
__global__ __launch_bounds__(256)
void scan3_enc_kernel(int* __restrict__ rowptr, const int* __restrict__ bsum,
                      const int* __restrict__ degi,
                      float* __restrict__ dinv, float* __restrict__ dinvl, int N,
                      EncCfg c0, EncCfg c1)
{
    __shared__ ushort_t As[64][40];
    __shared__ ushort_t Bs[128][40];
    int bx = blockIdx.x;
    int ns3 = (N + 255) >> 8;
    int gG = (N + 63) >> 6;
    if (bx < ns3) {
        int i = bx * 256 + threadIdx.x;
        if (i == 0) rowptr[0] = 0;
        if (i < N) {
            rowptr[i + 1] += bsum[i / SCH];
            float deg = (float)degi[i];
            dinv[i] = (deg > 0.f) ? rsqrtf(fmaxf(deg, 1.f)) : 0.f;
            dinvl[i] = rsqrtf(deg + 1.f);
        }
        return;
    }
    int b2 = bx - ns3;
    if (b2 < gG) gemm_f32_ln_dev(As, Bs, c0, b2, N);
    else gemm_f32_ln_dev(As, Bs, c1, b2 - gG, N);
}

// ---------- device: fuse GEMM K=256 with LN+ReLU epilogue ----------
__device__ __forceinline__ void gemm_ln256_dev(ushort_t (*As)[40], ushort_t (*Bs)[40],
                                               const ushort_t* __restrict__ A,
                                               const ushort_t* __restrict__ Wt,
                                               ushort_t* __restrict__ Cb, int M,
                                               const float* __restrict__ bias,
                                               const float* __restrict__ g,
                                               const float* __restrict__ be, int bx)
{
    const int K = 256;
    const int tid = threadIdx.x;
    const int m0 = bx * 64;
    const int lane = tid & 63;
    const int wv = tid >> 6;
    const int q = lane >> 4;
    const int l16 = lane & 15;
    const int sar = tid >> 2;
    const int sak = (tid & 3) << 3;
    const int sbn = tid >> 1;
    const int sbk = (tid & 1) << 4;
    const bool arow_ok = (m0 + sar) < M;
    const ushort_t* Arow = A + (size_t)(m0 + sar) * K;
    const ushort_t* Wrow = Wt + (size_t)sbn * K;

    f32x4 acc[8];
#pragma unroll
    for (int t = 0; t < 8; t++) acc[t] = (f32x4){0.f, 0.f, 0.f, 0.f};

#pragma unroll
    for (int k0 = 0; k0 < K; k0 += 32) {
        uint4 apk = arow_ok ? *(const uint4*)(Arow + k0 + sak) : make_uint4(0, 0, 0, 0);
        uint4 b0 = *(const uint4*)(Wrow + k0 + sbk);
        uint4 b1 = *(const uint4*)(Wrow + k0 + sbk + 8);
        __syncthreads();
        *(uint4*)&As[sar][sak] = apk;
        *(uint4*)&Bs[sbn][sbk] = b0;
        *(uint4*)&Bs[sbn][sbk + 8] = b1;
        __syncthreads();
        bf16x8 af = *(const bf16x8*)&As[16 * wv + l16][q * 8];
#pragma unroll
        for (int t = 0; t < 8; t++) {
            bf16x8 bf = *(const bf16x8*)&Bs[t * 16 + l16][q * 8];
            acc[t] = __builtin_amdgcn_mfma_f32_16x16x32_bf16(af, bf, acc[t], 0, 0, 0);
        }
    }
    const int row_base = m0 + 16 * wv + q * 4;
#pragma unroll
    for (int t = 0; t < 8; t++) {
        float bb = bias[t * 16 + l16];
#pragma unroll
        for (int r = 0; r < 4; r++) acc[t][r] += bb;
    }
    float mean[4], inv[4];
#pragma unroll
    for (int r = 0; r < 4; r++) {
        float s = 0.f, sq = 0.f;
#pragma unroll
        for (int t = 0; t < 8; t++) { float v = acc[t][r]; s += v; sq = fmaf(v, v, sq); }
#pragma unroll
        for (int off = 1; off <= 8; off <<= 1) { s += __shfl_xor(s, off); sq += __shfl_xor(sq, off); }
        mean[r] = s * (1.f / 128.f);
        float var = sq * (1.f / 128.f) - mean[r] * mean[r];
        inv[r] = rsqrtf(var + 1e-5f);
    }
#pragma unroll
    for (int t = 0; t < 8; t++) {
        int col = t * 16 + l16;
        float gg = g[col], b2 = be[col];
#pragma unroll
        for (int r = 0; r < 4; r++) {
            float y = fmaxf(fmaf((acc[t][r] - mean[r]) * inv[r], gg, b2), 0.f);
            float other = __shfl_xor(y, 1);
            int row = row_base + r;
            if (!(l16 & 1) && row < M) {
                unsigned int pk = f2bu(y) | (f2bu(other) << 16);
                *(unsigned int*)(Cb + (size_t)row * 128 + col) = pk;
            }
        }
    }
}

// ---------- merged: fuse GEMM + csr_fill + router top-k ----------
__global__ __launch_bounds__(256)
void ln_csr_topk_kernel(const ushort_t* __restrict__ A, const ushort_t* __restrict__ Wt,
                        ushort_t* __restrict__ Cb, int N,
                        const float* __restrict__ bias,
                        const float* __restrict__ g, const float* __restrict__ be,
                        const int* __restrict__ src, const int* __restrict__ dst,
                        const int* __restrict__ rowptr, int* __restrict__ cursor,
                        int* __restrict__ csr,
                        const float* __restrict__ dinv, const float* __restrict__ dinvl,
                        float* __restrict__ ecA, float* __restrict__ ecB, int E,
                        const float* __restrict__ la, const float* __restrict__ lb,
                        float* __restrict__ gates)
{
    __shared__ ushort_t As[64][40];
    __shared__ ushort_t Bs[128][40];
    int bx = blockIdx.x;
    int gG = (N + 63) >> 6;
    int nedge = (E + 255) >> 8;
    if (bx < gG) {
        gemm_ln256_dev(As, Bs, A, Wt, Cb, N, bias, g, be, bx);
        return;
    }
    if (bx < gG + nedge) {
        int e = (bx - gG) * 256 + threadIdx.x;
        if (e >= E) return;
        int d = dst[e];
        int s = src[e];
        int pos = atomicAdd(&cursor[d], 1);
        int o = rowptr[d] + pos;
        csr[o] = s;
        ecA[o] = dinv[d] * dinv[s];
        ecB[o] = dinvl[d] * dinvl[s];
        return;
    }
    int n = (bx - gG - nedge) * 256 + threadIdx.x;
    if (n >= N) return;
    float4 a = *(const float4*)(la + (size_t)n * 4);
    float4 b = *(const float4*)(lb + (size_t)n * 4);
    float l[4] = {(a.x + b.x) * (1.f / 1.5f), (a.y + b.y) * (1.f / 1.5f),
                  (a.z + b.z) * (1.f / 1.5f), (a.w + b.w) * (1.f / 1.5f)};
    float mx = fmaxf(fmaxf(l[0], l[1]), fmaxf(l[2], l[3]));
    float e4[4], ssum = 0.f;
#pragma unroll
    for (int i = 0; i < 4; i++) { e4[i] = expf(l[i] - mx); ssum += e4[i]; }
    float p[4];
#pragma unroll
    for (int i = 0; i < 4; i++) p[i] = e4[i] / ssum;
    int i0 = 0;
    for (int i = 1; i < 4; i++) if (p[i] > p[i0]) i0 = i;
    int i1 = -1;
    for (int i = 0; i < 4; i++) {
        if (i == i0) continue;
        if (i1 < 0 || p[i] > p[i1]) i1 = i;
    }
    float wsum = fmaxf(p[i0] + p[i1], 1e-9f);
    float gg[4] = {0.f, 0.f, 0.f, 0.f};
    gg[i0] = p[i0] / wsum;
    gg[i1] = p[i1] / wsum;
    *(float4*)(gates + (size_t)n * 4) = make_float4(gg[0], gg[1], gg[2], gg[3]);
}

// ---------- device: bf16 LDS GEMM (K templated), plain epilogue ----------
template <int K>
__device__ __forceinline__ void gemm_bf_dev(ushort_t (*As)[40], ushort_t (*Bs)[40],
                                            const ushort_t* __restrict__ A,
                                            const ushort_t* __restrict__ Wt,
                                            ushort_t* __restrict__ Cb, int M,
                                            const float* __restrict__ bias, int relu, int bx)
{
    const int tid = threadIdx.x;
    const int m0 = bx * 64;
    const int lane = tid & 63;
    const int wv = tid >> 6;
    const int q = lane >> 4;
    const int l16 = lane & 15;
    const int sar = tid >> 2;
    const int sak = (tid & 3) << 3;
    const int sbn = tid >> 1;
    const int sbk = (tid & 1) << 4;
    const bool arow_ok = (m0 + sar) < M;
    const ushort_t* Arow = A + (size_t)(m0 + sar) * K;
    const ushort_t* Wrow = Wt + (size_t)sbn * K;

    f32x4 acc[8];
#pragma unroll
    for (int t = 0; t < 8; t++) acc[t] = (f32x4){0.f, 0.f, 0.f, 0.f};

#pragma unroll
    for (int k0 = 0; k0 < K; k0 += 32) {
        uint4 apk = arow_ok ? *(const uint4*)(Arow + k0 + sak) : make_uint4(0, 0, 0, 0);
        uint4 b0 = *(const uint4*)(Wrow + k0 + sbk);
        uint4 b1 = *(const uint4*)(Wrow + k0 + sbk + 8);
        __syncthreads();
        *(uint4*)&As[sar][sak] = apk;
        *(uint4*)&Bs[sbn][sbk] = b0;
        *(uint4*)&Bs[sbn][sbk + 8] = b1;
        __syncthreads();
        bf16x8 af = *(const bf16x8*)&As[16 * wv + l16][q * 8];
#pragma unroll
        for (int t = 0; t < 8; t++) {
            bf16x8 bf = *(const bf16x8*)&Bs[t * 16 + l16][q * 8];
            acc[t] = __builtin_amdgcn_mfma_f32_16x16x32_bf16(af, bf, acc[t], 0, 0, 0);
        }
    }
#pragma unroll
    for (int t = 0; t < 8; t++) {
        int col = t * 16 + l16;
        float bb = bias ? bias[col] : 0.f;
#pragma unroll
        for (int r = 0; r < 4; r++) {
            int row = m0 + 16 * wv + q * 4 + r;
            float val = acc[t][r] + bb;
            if (relu) val = fmaxf(val, 0.f);
            float other = __shfl_xor(val, 1);
            if (!(lane & 1) && row < M) {
                unsigned int pk = f2bu(val) | (f2bu(other) << 16);
                *(unsigned int*)(Cb + (size_t)row * 128 + col) = pk;
            }
        }
    }
}

// ---------- device: bf16 LDS GEMM with output stride (K=128), plain bias ----------
__device__ __forceinline__ void gemm_bfs_dev(ushort_t (*As)[40], ushort_t (*Bs)[40],
                                             const ushort_t* __restrict__ A,
                                             const ushort_t* __restrict__ Wt,
                                             ushort_t* __restrict__ Cb, int ldc, int M,
                                             const float* __restrict__ bias, int bx)
{
    const int K = 128;
    const int tid = threadIdx.x;
    const int m0 = bx * 64;
    const int lane = tid & 63;
    const int wv = tid >> 6;
    const int q = lane >> 4;
    const int l16 = lane & 15;
    const int sar = tid >> 2;
    const int sak = (tid & 3) << 3;
    const int sbn = tid >> 1;
    const int sbk = (tid & 1) << 4;
    const bool arow_ok = (m0 + sar) < M;
    const ushort_t* Arow = A + (size_t)(m0 + sar) * K;
    const ushort_t* Wrow = Wt + (size_t)sbn * K;

    f32x4 acc[8];
#pragma unroll
    for (int t = 0; t < 8; t++) acc[t] = (f32x4){0.f, 0.f, 0.f, 0.f};

#pragma unroll
    for (int k0 = 0; k0 < K; k0 += 32) {
        uint4 apk = arow_ok ? *(const uint4*)(Arow + k0 + sak) : make_uint4(0, 0, 0, 0);
        uint4 b0 = *(const uint4*)(Wrow + k0 + sbk);
        uint4 b1 = *(const uint4*)(Wrow + k0 + sbk + 8);
        __syncthreads();
        *(uint4*)&As[sar][sak] = apk;
        *(uint4*)&Bs[sbn][sbk] = b0;
        *(uint4*)&Bs[sbn][sbk + 8] = b1;
        __syncthreads();
        bf16x8 af = *(const bf16x8*)&As[16 * wv + l16][q * 8];
#pragma unroll
        for (int t = 0; t < 8; t++) {
            bf16x8 bf = *(const bf16x8*)&Bs[t * 16 + l16][q * 8];
            acc[t] = __builtin_amdgcn_mfma_f32_16x16x32_bf16(af, bf, acc[t], 0, 0, 0);
        }
    }
#pragma unroll
    for (int t = 0; t < 8; t++) {
        int col = t * 16 + l16;
        float bb = bias[col];
#pragma unroll
        for (int r = 0; r < 4; r++) {
            int row = m0 + 16 * wv + q * 4 + r;
            float val = acc[t][r] + bb;
            float other = __shfl_xor(val, 1);
            if (!(lane & 1) && row < M) {
                unsigned int pk = f2bu(val) | (f2bu(other) << 16);
                *(unsigned int*)(Cb + (size_t)row * ldc + col) = pk;
            }
        }
    }
}

// ---------- device: dual GEMM C = A1@W1 + A2@W2 ----------
__device__ __forceinline__ void gemm_dual_dev(ushort_t (*As)[40], ushort_t (*Bs)[40],
                                              const ushort_t* __restrict__ A1,
                                              const ushort_t* __restrict__ Wt1,
                                              const ushort_t* __restrict__ A2,
                                              const ushort_t* __restrict__ Wt2,
                                              ushort_t* __restrict__ Cb, int M,
                                              const float* __restrict__ bias, int relu, int bx)
{
    const int K = 128;
    const int tid = threadIdx.x;
    const int m0 = bx * 64;
    const int lane = tid & 63;
    const int wv = tid >> 6;
    const int q = lane >> 4;
    const int l16 = lane & 15;
    const int sar = tid >> 2;
    const int sak = (tid & 3) << 3;
    const int sbn = tid >> 1;
    const int sbk = (tid & 1) << 4;
    const bool arow_ok = (m0 + sar) < M;

    f32x4 acc[8];
#pragma unroll
    for (int t = 0; t < 8; t++) acc[t] = (f32x4){0.f, 0.f, 0.f, 0.f};

    for (int ph = 0; ph < 2; ph++) {
        const ushort_t* Arow = (ph ? A2 : A1) + (size_t)(m0 + sar) * K;
        const ushort_t* Wrow = (ph ? Wt2 : Wt1) + (size_t)sbn * K;
        for (int k0 = 0; k0 < K; k0 += 32) {
            uint4 apk = arow_ok ? *(const uint4*)(Arow + k0 + sak) : make_uint4(0, 0, 0, 0);
            uint4 b0 = *(const uint4*)(Wrow + k0 + sbk);
            uint4 b1 = *(const uint4*)(Wrow + k0 + sbk + 8);
            __syncthreads();
            *(uint4*)&As[sar][sak] = apk;
            *(uint4*)&Bs[sbn][sbk] = b0;
            *(uint4*)&Bs[sbn][sbk + 8] = b1;
            __syncthreads();
            bf16x8 af = *(const bf16x8*)&As[16 * wv + l16][q * 8];
#pragma unroll
            for (int t = 0; t < 8; t++) {
                bf16x8 bf = *(const bf16x8*)&Bs[t * 16 + l16][q * 8];
                acc[t] = __builtin_amdgcn_mfma_f32_16x16x32_bf16(af, bf, acc[t], 0, 0, 0);
            }
        }
    }
#pragma unroll
    for (int t = 0; t < 8; t++) {
        int col = t * 16 + l16;
        float bb = bias ? bias[col] : 0.f;
#pragma unroll
        for (int r = 0; r < 4; r++) {
            int row = m0 + 16 * wv + q * 4 + r;
            float val = acc[t][r] + bb;
            if (relu) val = fmaxf(val, 0.f);
            float other = __shfl_xor(val, 1);
            if (!(lane & 1) && row < M) {
                unsigned int pk = f2bu(val) | (f2bu(other) << 16);
                *(unsigned int*)(Cb + (size_t)row * 128 + col) = pk;
            }
        }
    }
}

// ---------- device: no-LDS wave-tile GEMM (K=128, col-split 4) ----------
__device__ __forceinline__ void gemm_wv_dev(const ushort_t* __restrict__ A,
                                            const ushort_t* __restrict__ Wt,
                                            ushort_t* __restrict__ Cb, int M,
                                            const float* __restrict__ bias, int relu,
                                            int w, int lane)
{
    const int K = 128;
    int ct = w & 3;
    int rt = w >> 2;
    int row0 = rt * 16;
    if (row0 >= M) return;
    int l16 = lane & 15, q = lane >> 4;
    int arow = row0 + l16;
    bool aok = arow < M;
    const ushort_t* Ar = A + (size_t)arow * K + q * 8;
    const ushort_t* W0 = Wt + (size_t)(ct * 32 + l16) * K + q * 8;
    const ushort_t* W1 = W0 + (size_t)16 * K;
    bf16x8 zz = {0, 0, 0, 0, 0, 0, 0, 0};
    f32x4 a0 = {0.f, 0.f, 0.f, 0.f}, a1 = {0.f, 0.f, 0.f, 0.f};
#pragma unroll
    for (int k0 = 0; k0 < K; k0 += 32) {
        bf16x8 af = aok ? *(const bf16x8*)(Ar + k0) : zz;
        bf16x8 b0 = *(const bf16x8*)(W0 + k0);
        bf16x8 b1 = *(const bf16x8*)(W1 + k0);
        a0 = __builtin_amdgcn_mfma_f32_16x16x32_bf16(af, b0, a0, 0, 0, 0);
        a1 = __builtin_amdgcn_mfma_f32_16x16x32_bf16(af, b1, a1, 0, 0, 0);
    }
    f32x4 av[2] = {a0, a1};
#pragma unroll
    for (int t = 0; t < 2; t++) {
        int col = ct * 32 + t * 16 + l16;
        float bb = bias ? bias[col] : 0.f;
#pragma unroll
        for (int r = 0; r < 4; r++) {
            int row = row0 + q * 4 + r;
            float val = av[t][r] + bb;
            if (relu) val = fmaxf(val, 0.f);
            float other = __shfl_xor(val, 1);
            if (!(l16 & 1) && row < M) {
                unsigned int pk = f2bu(val) | (f2bu(other) << 16);
                *(unsigned int*)(Cb + (size_t)row * 128 + col) = pk;
            }
        }
    }
}

// ---------- device: dual gather layer-1 (software-pipelined rows) ----------
__device__ __forceinline__ void gather2_dev(const ushort_t* __restrict__ Xb,
                                            ushort_t* __restrict__ OutA, ushort_t* __restrict__ OutB,
                                            const int* __restrict__ rowptr, const int* __restrict__ csr,
                                            const float* __restrict__ ecA, const float* __restrict__ ecB,
                                            const float* __restrict__ dinvl, int M, int bx)
{
    int node = bx * 4 + (threadIdx.x >> 6);
    int lane = threadIdx.x & 63;
    if (node >= M) return;
    int beg = rowptr[node], end = rowptr[node + 1];
    int slot = lane >> 4, g = lane & 15;
    float aA[8] = {0, 0, 0, 0, 0, 0, 0, 0};
    float aB[8] = {0, 0, 0, 0, 0, 0, 0, 0};

    float cAa = 0.f, cBa = 0.f, cAb = 0.f, cBb = 0.f;
    int na = 0, nb = 0;
    float nAa = 0.f, nBa = 0.f, nAb = 0.f, nBb = 0.f;
    uint4 xA, xB;
    {
        int r0 = beg + slot, r1 = beg + 4 + slot;
        int ia = 0, ib = 0;
        if (r0 < end) { ia = csr[r0]; cAa = ecA[r0]; cBa = ecB[r0]; }
        if (r1 < end) { ib = csr[r1]; cAb = ecA[r1]; cBb = ecB[r1]; }
        xA = *(const uint4*)(Xb + (size_t)ia * 128 + g * 8);
        xB = *(const uint4*)(Xb + (size_t)ib * 128 + g * 8);
    }
    {
        int r0 = beg + 8 + slot, r1 = beg + 12 + slot;
        if (r0 < end) { na = csr[r0]; nAa = ecA[r0]; nBa = ecB[r0]; }
        if (r1 < end) { nb = csr[r1]; nAb = ecA[r1]; nBb = ecB[r1]; }
    }
    for (int e = beg; e < end; e += 8) {
        uint4 xA2 = *(const uint4*)(Xb + (size_t)na * 128 + g * 8);
        uint4 xB2 = *(const uint4*)(Xb + (size_t)nb * 128 + g * 8);
        int r0 = e + 16 + slot, r1 = e + 20 + slot;
        int ma = 0, mb = 0;
        float mAa = 0.f, mBa = 0.f, mAb = 0.f, mBb = 0.f;
        if (r0 < end) { ma = csr[r0]; mAa = ecA[r0]; mBa = ecB[r0]; }
        if (r1 < end) { mb = csr[r1]; mAb = ecA[r1]; mBb = ecB[r1]; }
        fma8(xA, cAa, aA); fma8(xA, cBa, aB);
        fma8(xB, cAb, aA); fma8(xB, cBb, aB);
        xA = xA2; xB = xB2;
        cAa = nAa; cBa = nBa; cAb = nAb; cBb = nBb;
        na = ma; nb = mb;
        nAa = mAa; nBa = mBa; nAb = mAb; nBb = mBb;
    }
#pragma unroll
    for (int j = 0; j < 8; j++) {
        aA[j] += __shfl_xor(aA[j], 16); aA[j] += __shfl_xor(aA[j], 32);
        aB[j] += __shfl_xor(aB[j], 16); aB[j] += __shfl_xor(aB[j], 32);
    }
    {
        float c = dinvl[node]; c *= c;
        uint4 xs = *(const uint4*)(Xb + (size_t)node * 128 + g * 8);
        fma8(xs, c, aB);
    }
    if (lane < 16) {
        float oA[8], oB[8];
#pragma unroll
        for (int j = 0; j < 8; j++) { oA[j] = -aA[j]; oB[j] = aB[j]; }
        size_t ofs = (size_t)node * 128 + g * 8;
        *(uint4*)(OutA + ofs) = pack8(oA);
        *(uint4*)(OutB + ofs) = pack8(oB);
    }
}

// ---------- device: dual-input gather layer-2 (software-pipelined rows) ----------
__device__ __forceinline__ void gather_l2_dev(const ushort_t* __restrict__ XA,
                                              const ushort_t* __restrict__ XB,
                                              ushort_t* __restrict__ OutA, ushort_t* __restrict__ OutB,
                                              const int* __restrict__ rowptr, const int* __restrict__ csr,
                                              const float* __restrict__ ecA, const float* __restrict__ ecB,
                                              const float* __restrict__ dinvl, int M, int bx)
{
    int node = bx * 4 + (threadIdx.x >> 6);
    int lane = threadIdx.x & 63;
    if (node >= M) return;
    int beg = rowptr[node], end = rowptr[node + 1];
    int slot = lane >> 4, g = lane & 15;
    float aA[8] = {0, 0, 0, 0, 0, 0, 0, 0};
    float aB[8] = {0, 0, 0, 0, 0, 0, 0, 0};

    float cAa = 0.f, cBa = 0.f, cAb = 0.f, cBb = 0.f;
    int na = 0, nb = 0;
    float nAa = 0.f, nBa = 0.f, nAb = 0.f, nBb = 0.f;
    uint4 ra, rb, sa, sb;
    {
        int r0 = beg + slot, r1 = beg + 4 + slot;
        int ia = 0, ib = 0;
        if (r0 < end) { ia = csr[r0]; cAa = ecA[r0]; cBa = ecB[r0]; }
        if (r1 < end) { ib = csr[r1]; cAb = ecA[r1]; cBb = ecB[r1]; }
        ra = *(const uint4*)(XA + (size_t)ia * 128 + g * 8);
        rb = *(const uint4*)(XA + (size_t)ib * 128 + g * 8);
        sa = *(const uint4*)(XB + (size_t)ia * 128 + g * 8);
        sb = *(const uint4*)(XB + (size_t)ib * 128 + g * 8);
    }
    {
        int r0 = beg + 8 + slot, r1 = beg + 12 + slot;
        if (r0 < end) { na = csr[r0]; nAa = ecA[r0]; nBa = ecB[r0]; }
        if (r1 < end) { nb = csr[r1]; nAb = ecA[r1]; nBb = ecB[r1]; }
    }
    for (int e = beg; e < end; e += 8) {
        uint4 ra2 = *(const uint4*)(XA + (size_t)na * 128 + g * 8);
        uint4 rb2 = *(const uint4*)(XA + (size_t)nb * 128 + g * 8);
        uint4 sa2 = *(const uint4*)(XB + (size_t)na * 128 + g * 8);
        uint4 sb2 = *(const uint4*)(XB + (size_t)nb * 128 + g * 8);
        int r0 = e + 16 + slot, r1 = e + 20 + slot;
        int ma = 0, mb = 0;
        float mAa = 0.f, mBa = 0.f, mAb = 0.f, mBb = 0.f;
        if (r0 < end) { ma = csr[r0]; mAa = ecA[r0]; mBa = ecB[r0]; }
        if (r1 < end) { mb = csr[r1]; mAb = ecA[r1]; mBb = ecB[r1]; }
        fma8(ra, cAa, aA); fma8(rb, cAb, aA);
        fma8(sa, cBa, aB); fma8(sb, cBb, aB);
        ra = ra2; rb = rb2; sa = sa2; sb = sb2;
        cAa = nAa; cBa = nBa; cAb = nAb; cBb = nBb;
        na = ma; nb = mb;
        nAa = mAa; nBa = mBa; nAb = mAb; nBb = mBb;
    }
#pragma unroll
    for (int j = 0; j < 8; j++) {
        aA[j] += __shfl_xor(aA[j], 16); aA[j] += __shfl_xor(aA[j], 32);
        aB[j] += __shfl_xor(aB[j], 16); aB[j] += __shfl_xor(aB[j], 32);
    }
    {
        float c = dinvl[node]; c *= c;
        uint4 xs = *(const uint4*)(XB + (size_t)node * 128 + g * 8);
        fma8(xs, c, aB);
    }
    if (lane < 16) {
        float oA[8], oB[8];
#pragma unroll
        for (int j = 0; j < 8; j++) { oA[j] = -aA[j]; oB[j] = aB[j]; }
        size_t ofs = (size_t)node * 128 + g * 8;
        *(uint4*)(OutA + ofs) = pack8(oA);
        *(uint4*)(OutB + ofs) = pack8(oB);
    }
}

// ---------- device: attention with fused skip-add (+relu), software-pipelined ----------
__device__ __forceinline__ void gt_attn_dev(const ushort_t* __restrict__ Qb,
                                            const ushort_t* __restrict__ KV,
                                            const int* __restrict__ rowptr, const int* __restrict__ csr,
                                            const ushort_t* __restrict__ sk, int relu,
                                            ushort_t* __restrict__ Outb, int M, int bx)
{
    const float SCL = 0.17677669529663689f * 1.4426950408889634f;
    int node = bx * 4 + (threadIdx.x >> 6);
    int lane = threadIdx.x & 63;
    if (node >= M) return;
    int beg = rowptr[node], end = rowptr[node + 1];
    int slot = lane >> 4, g = lane & 15;
    uint4 qv = *(const uint4*)(Qb + (size_t)node * 128 + g * 8);
    float qf[8];
    unpack8(qv, qf);
#pragma unroll
    for (int j = 0; j < 8; j++) qf[j] *= SCL;
    float ax[8] = {0, 0, 0, 0, 0, 0, 0, 0};
    float den = 0.f;

    bool va = false, vb = false;
    int na = 0, nb = 0;
    bool wa = false, wb = false;
    uint4 kA, kB, uA, uB;
    {
        int r0 = beg + slot, r1 = beg + 4 + slot;
        va = r0 < end; vb = r1 < end;
        int ia = va ? csr[r0] : 0;
        int ib = vb ? csr[r1] : 0;
        const ushort_t* p0 = KV + (size_t)ia * 256 + g * 8;
        const ushort_t* p1 = KV + (size_t)ib * 256 + g * 8;
        kA = *(const uint4*)p0; uA = *(const uint4*)(p0 + 128);
        kB = *(const uint4*)p1; uB = *(const uint4*)(p1 + 128);
    }
    {
        int r0 = beg + 8 + slot, r1 = beg + 12 + slot;
        wa = r0 < end; wb = r1 < end;
        na = wa ? csr[r0] : 0;
        nb = wb ? csr[r1] : 0;
    }
    for (int e = beg; e < end; e += 8) {
        const ushort_t* p0 = KV + (size_t)na * 256 + g * 8;
        const ushort_t* p1 = KV + (size_t)nb * 256 + g * 8;
        uint4 kA2 = *(const uint4*)p0;
        uint4 uA2 = *(const uint4*)(p0 + 128);
        uint4 kB2 = *(const uint4*)p1;
        uint4 uB2 = *(const uint4*)(p1 + 128);
        int r0 = e + 16 + slot, r1 = e + 20 + slot;
        bool xa = r0 < end, xb = r1 < end;
        int ma = xa ? csr[r0] : 0;
        int mb = xb ? csr[r1] : 0;
        float d0 = dot8(kA, qf);
        float d1 = dot8(kB, qf);
        d0 += __shfl_xor(d0, 1); d0 += __shfl_xor(d0, 2);
        d1 += __shfl_xor(d1, 1); d1 += __shfl_xor(d1, 2);
        float w0 = va ? exp2f(fminf(d0, 80.f)) : 0.f;
        float w1 = vb ? exp2f(fminf(d1, 80.f)) : 0.f;
        den += w0 + w1;
        fma8(uA, w0, ax);
        fma8(uB, w1, ax);
        kA = kA2; kB = kB2; uA = uA2; uB = uB2;
        va = wa; vb = wb;
        wa = xa; wb = xb; na = ma; nb = mb;
    }
#pragma unroll
    for (int j = 0; j < 8; j++) {
        ax[j] += __shfl_xor(ax[j], 16); ax[j] += __shfl_xor(ax[j], 32);
    }
    den += __shfl_xor(den, 16); den += __shfl_xor(den, 32);
    float dd = fmaxf(den, 1e-9f);
    if (lane < 16) {
        uint4 sv = *(const uint4*)(sk + (size_t)node * 128 + g * 8);
        float sf[8];
        unpack8(sv, sf);
        float o[8];
#pragma unroll
        for (int j = 0; j < 8; j++) {
            float v = ax[j] / dd + sf[j];
            o[j] = relu ? fmaxf(v, 0.f) : v;
        }
        *(uint4*)(Outb + (size_t)node * 128 + g * 8) = pack8(o);
    }
}

// ---------- merged: gather2 + MLP-L1 (no LDS) ----------
__global__ void flatA_kernel(const ushort_t* __restrict__ hb,
                             ushort_t* __restrict__ x1, ushort_t* __restrict__ x2,
                             const int* __restrict__ rowptr, const int* __restrict__ csr,
                             const float* __restrict__ ecA, const float* __restrict__ ecB,
                             const float* __restrict__ dinvl, int N,
                             const ushort_t* __restrict__ wmlp1, ushort_t* __restrict__ xm,
                             const float* __restrict__ b18)
{
    int bx = blockIdx.x;
    int gN4 = (N + 3) >> 2;
    if (bx < gN4) {
        gather2_dev(hb, x1, x2, rowptr, csr, ecA, ecB, dinvl, N, bx);
    } else {
        int w = (bx - gN4) * 4 + (threadIdx.x >> 6);
        gemm_wv_dev(hb, wmlp1, xm, N, b18, 1, w, threadIdx.x & 63);
    }
}

// ---------- merged LDS GEMMs A: Q,K,V,S panels + Cheb dual1 + GCN1 ----------
__global__ __launch_bounds__(256)
void megaA_kernel(const ushort_t* __restrict__ hb,
                  const ushort_t* __restrict__ wqkvs,
                  ushort_t* __restrict__ qb, ushort_t* __restrict__ kvb, ushort_t* __restrict__ skb,
                  const float* __restrict__ bq, const float* __restrict__ bk,
                  const float* __restrict__ bv, const float* __restrict__ bs,
                  const ushort_t* __restrict__ x1, const ushort_t* __restrict__ wch0,
                  const ushort_t* __restrict__ wch1, ushort_t* __restrict__ x0,
                  const float* __restrict__ bch,
                  const ushort_t* __restrict__ x2, const ushort_t* __restrict__ wgcn,
                  ushort_t* __restrict__ xg1, const float* __restrict__ bgcn,
                  int M)
{
    __shared__ ushort_t As[64][40];
    __shared__ ushort_t Bs[128][40];
    int y = blockIdx.y, bx = blockIdx.x;
    const size_t PS = (size_t)128 * 128;   // weight panel stride
    if (y == 0) gemm_bfs_dev(As, Bs, hb, wqkvs, qb, 128, M, bq, bx);
    else if (y == 1) gemm_bfs_dev(As, Bs, hb, wqkvs + PS, kvb, 256, M, bk, bx);
    else if (y == 2) gemm_bfs_dev(As, Bs, hb, wqkvs + 2 * PS, kvb + 128, 256, M, bv, bx);
    else if (y == 3) gemm_bfs_dev(As, Bs, hb, wqkvs + 3 * PS, skb, 128, M, bs, bx);
    else if (y == 4) gemm_dual_dev(As, Bs, hb, wch0, x1, wch1, x0, M, bch, 1, bx);
    else gemm_bf_dev<128>(As, Bs, x2, wgcn, xg1, M, bgcn, 1, bx);
}

// ---------- merged: attn1 + gather_l2 (no LDS) ----------
__global__ void flatB_kernel(const ushort_t* __restrict__ qb, const ushort_t* __restrict__ kvb,
                             const int* __restrict__ rowptr, const int* __restrict__ csr,
                             const ushort_t* __restrict__ skb, ushort_t* __restrict__ aout,
                             const ushort_t* __restrict__ x0, const ushort_t* __restrict__ xg1,
                             ushort_t* __restrict__ x3, ushort_t* __restrict__ x2,
                             const float* __restrict__ ecA, const float* __restrict__ ecB,
                             const float* __restrict__ dinvl, int N)
{
    int bx = blockIdx.x;
    int gN4 = (N + 3) >> 2;
    if (bx < gN4) gt_attn_dev(qb, kvb, rowptr, csr, skb, 1, aout, N, bx);
    else gather_l2_dev(x0, xg1, x3, x2, rowptr, csr, ecA, ecB, dinvl, N, bx - gN4);
}

// ---------- merged LDS GEMMs B: Q,K,V,S panels + Cheb dual2 + GCN2 + MLP2 ----------
__global__ __launch_bounds__(256)
void megaB_kernel(const ushort_t* __restrict__ x1,
                  const ushort_t* __restrict__ wqkvs,
                  ushort_t* __restrict__ qb, ushort_t* __restrict__ kvb, ushort_t* __restrict__ skb,
                  const float* __restrict__ bq, const float* __restrict__ bk,
                  const float* __restrict__ bv, const float* __restrict__ bs,
                  const ushort_t* __restrict__ x0, const ushort_t* __restrict__ wch0,
                  const ushort_t* __restrict__ x3, const ushort_t* __restrict__ wch1,
                  ushort_t* __restrict__ e1b, const float* __restrict__ bch,
                  const ushort_t* __restrict__ x2, const ushort_t* __restrict__ wgcn,
                  ushort_t* __restrict__ e3b, const float* __restrict__ bgcn,
                  const ushort_t* __restrict__ xm, const ushort_t* __restrict__ wmlp2,
                  ushort_t* __restrict__ e0b, const float* __restrict__ bmlp2,
                  int M)
{
    __shared__ ushort_t As[64][40];
    __shared__ ushort_t Bs[128][40];
    int y = blockIdx.y, bx = blockIdx.x;
    const size_t PS = (size_t)128 * 128;
    if (y == 0) gemm_bfs_dev(As, Bs, x1, wqkvs, qb, 128, M, bq, bx);
    else if (y == 1) gemm_bfs_dev(As, Bs, x1, wqkvs + PS, kvb, 256, M, bk, bx);
    else if (y == 2) gemm_bfs_dev(As, Bs, x1, wqkvs + 2 * PS, kvb + 128, 256, M, bv, bx);
    else if (y == 3) gemm_bfs_dev(As, Bs, x1, wqkvs + 3 * PS, skb, 128, M, bs, bx);
    else if (y == 4) gemm_dual_dev(As, Bs, x0, wch0, x3, wch1, e1b, M, bch, 0, bx);
    else if (y == 5) gemm_bf_dev<128>(As, Bs, x2, wgcn, e3b, M, bgcn, 0, bx);
    else gemm_bf_dev<128>(As, Bs, xm, wmlp2, e0b, M, bmlp2, 0, bx);
}

// ---------- merged: attn2 + poolA (h, e0, e1, e3) ----------
__global__ void attn2_pool_kernel(const ushort_t* __restrict__ Qb, const ushort_t* __restrict__ KV,
                                  const int* __restrict__ rowptr, const int* __restrict__ csr,
                                  const ushort_t* __restrict__ sk, ushort_t* __restrict__ e2b,
                                  int N,
                                  const ushort_t* __restrict__ hb,
                                  const ushort_t* __restrict__ e0, const ushort_t* __restrict__ e1,
                                  const ushort_t* __restrict__ e3,
                                  const float* __restrict__ gates,
                                  const float* __restrict__ png, const float* __restrict__ pnb,
                                  const float* __restrict__ esc,
                                  const int* __restrict__ bstart, const int* __restrict__ bend,
                                  float* __restrict__ partial)
{
    int bx = blockIdx.x;
    int gN4 = (N + 3) >> 2;
    if (bx < gN4) {
        gt_attn_dev(Qb, KV, rowptr, csr, sk, 0, e2b, N, bx);
        return;
    }
    int idx = bx - gN4;              // 0 .. B*PCH/4-1
    int b = idx >> 3;                // PCH/4 == 8
    int cq = ((idx & 7) << 2) + (threadIdx.x >> 6);
    int lane = threadIdx.x & 63;
    int s0 = bstart[b], eN = bend[b];
    const ushort_t* eps[3] = {e0, e1, e3};
    const int eid[3] = {0, 1, 3};
    float ga[3], gb[3], ba[3], bb[3], es[3];
#pragma unroll
    for (int j = 0; j < 3; j++) {
        int ee = eid[j];
        ga[j] = png[ee * 128 + lane * 2];
        gb[j] = png[ee * 128 + lane * 2 + 1];
        ba[j] = pnb[ee * 128 + lane * 2];
        bb[j] = pnb[ee * 128 + lane * 2 + 1];
        es[j] = esc[ee];
    }
    float sx = 0.f, sy = 0.f;
    for (int n = s0 + cq; n < eN; n += PCH) {
        size_t ofs = (size_t)n * 128 + lane * 2;
        float4 gg = *(const float4*)(gates + (size_t)n * 4);
        float gv[3] = {gg.x, gg.y, gg.w};
        unsigned int hu = *(const unsigned int*)(hb + ofs);
        float ox = bf2f(hu & 0xffff), oy = bf2f(hu >> 16);
#pragma unroll
        for (int j = 0; j < 3; j++) {
            unsigned int u = *(const unsigned int*)(eps[j] + ofs);
            float vx = bf2f(u & 0xffff), vy = bf2f(u >> 16);
            float su = vx + vy, sq = vx * vx + vy * vy;
#pragma unroll
            for (int off = 32; off; off >>= 1) { su += __shfl_xor(su, off); sq += __shfl_xor(sq, off); }
            float mean = su * (1.f / 128.f);
            float var = sq * (1.f / 128.f) - mean * mean;
            float inv = rsqrtf(var + 1e-5f);
            float cc = es[j] * gv[j];
            ox = fmaf(cc, (vx - mean) * inv * ga[j] + ba[j], ox);
            oy = fmaf(cc, (vy - mean) * inv * gb[j] + bb[j], oy);
        }
        sx += ox; sy += oy;
    }
    *(float2*)(partial + ((size_t)b * PCH + cq) * 128 + lane * 2) = make_float2(sx, sy);
}

// ---------- poolB: expert 2 contribution -> partial2 ----------
__global__ void poolB_kernel(const ushort_t* __restrict__ e2,
                             const float* __restrict__ gates,
                             const float* __restrict__ png, const float* __restrict__ pnb,
                             const float* __restrict__ esc,
                             const int* __restrict__ bstart, const int* __restrict__ bend,
                             float* __restrict__ partial2)
{
    int idx = blockIdx.x;
    int b = idx >> 3;
    int cq = ((idx & 7) << 2) + (threadIdx.x >> 6);
    int lane = threadIdx.x & 63;
    int s0 = bstart[b], eN = bend[b];
    float ga = png[2 * 128 + lane * 2], gb = png[2 * 128 + lane * 2 + 1];
    float ba = pnb[2 * 128 + lane * 2], bb = pnb[2 * 128 + lane * 2 + 1];
    float es = esc[2];
    float sx = 0.f, sy = 0.f;
    for (int n = s0 + cq; n < eN; n += PCH) {
        size_t ofs = (size_t)n * 128 + lane * 2;
        float gv = gates[(size_t)n * 4 + 2];
        unsigned int u = *(const unsigned int*)(e2 + ofs);
        float vx = bf2f(u & 0xffff), vy = bf2f(u >> 16);
        float su = vx + vy, sq = vx * vx + vy * vy;
#pragma unroll
        for (int off = 32; off; off >>= 1) { su += __shfl_xor(su, off); sq += __shfl_xor(sq, off); }
        float mean = su * (1.f / 128.f);
        float var = sq * (1.f / 128.f) - mean * mean;
        float inv = rsqrtf(var + 1e-5f);
        float cc = es * gv;
        sx = fmaf(cc, (vx - mean) * inv * ga + ba, sx);
        sy = fmaf(cc, (vy - mean) * inv * gb + bb, sy);
    }
    *(float2*)(partial2 + ((size_t)b * PCH + cq) * 128 + lane * 2) = make_float2(sx, sy);
}

// ---------- classification head (fused pool reduce over partial+partial2) ----------
__global__ void head_kernel(const float* __restrict__ partial,
                            const float* __restrict__ partial2,
                            const int* __restrict__ bstart, const int* __restrict__ bend,
                            const float* __restrict__ h1W, const float* __restrict__ h1b,
                            const float* __restrict__ h1g, const float* __restrict__ h1be,
                            const float* __restrict__ h2W, const float* __restrict__ h2b,
                            const float* __restrict__ h2g, const float* __restrict__ h2be,
                            const float* __restrict__ h3W, const float* __restrict__ h3b,
                            const float* __restrict__ lbias,
                            float* __restrict__ out, int B)
{
    __shared__ float p[128], z[128];
    int b = blockIdx.x, t = threadIdx.x;
    float sum = 0.f;
#pragma unroll
    for (int c = 0; c < PCH; c++) {
        size_t o = ((size_t)b * PCH + c) * 128 + t;
        sum += partial[o] + partial2[o];
    }
    float cnt = fmaxf((float)(bend[b] - bstart[b]), 1.f);
    p[t] = sum / cnt;
    __syncthreads();
    float a = h1b[t];
    for (int k = 0; k < 128; k++) a = fmaf(p[k], h1W[k * 128 + t], a);
    z[t] = a;
    __syncthreads();
    float s = 0.f, sq = 0.f;
    for (int k = 0; k < 128; k++) { float x = z[k]; s += x; sq += x * x; }
    float mean = s * (1.f / 128.f), var = sq * (1.f / 128.f) - mean * mean;
    float y = fmaxf((a - mean) * rsqrtf(var + 1e-5f) * h1g[t] + h1be[t], 0.f);
    __syncthreads();
    z[t] = y;
    __syncthreads();
    float a2 = 0.f;
    if (t < 64) {
        a2 = h2b[t];
        for (int k = 0; k < 128; k++) a2 = fmaf(z[k], h2W[k * 64 + t], a2);
    }
    __syncthreads();
    if (t < 64) p[t] = a2;
    __syncthreads();
    if (t < 2) {
        float s2 = 0.f, sq2 = 0.f;
        for (int k = 0; k < 64; k++) { float x = p[k]; s2 += x; sq2 += x * x; }
        float mean2 = s2 * (1.f / 64.f), var2 = sq2 * (1.f / 64.f) - mean2 * mean2;
        float inv2 = rsqrtf(var2 + 1e-5f);
        float o = h3b[t] + lbias[t];
        for (int k = 0; k < 64; k++) {
            float zc = fmaxf((p[k] - mean2) * inv2 * h2g[k] + h2be[k], 0.f);
            o = fmaf(zc, h3W[k * 2 + t], o);
        }
        out[b * 2 + t] = o;
    }
}

// ---------------- launch ----------------
extern "C" void kernel_launch(void* const* d_in, const int* in_sizes, int n_in,
                              void* d_out, int out_size, void* d_ws, size_t ws_size,
                              hipStream_t stream)
{
    (void)ws_size; (void)n_in;
    const int N = in_sizes[3];
    const int E = in_sizes[2] / 2;
    const int B = out_size / 2;

    const int* ei = (const int*)d_in[2];
    const int* src = ei;
    const int* dst = ei + E;
    const int* batch = (const int*)d_in[3];

    const float* W[47];
    for (int i = 0; i < 47; i++) W[i] = (const float*)d_in[i];

    size_t fN = (size_t)N;
    float* gates    = (float*)d_ws;                    // 4N
    float* dinv     = gates + 4 * fN;                  // N
    float* dinvl    = dinv + fN;                       // N
    float* partial  = dinvl + fN;                      // 128*B*PCH
    float* partial2 = partial + (size_t)128 * B * PCH; // 128*B*PCH
    float* logitsA  = partial2 + (size_t)128 * B * PCH;
    float* logitsB  = logitsA + 4 * fN;
    ushort_t* hb  = (ushort_t*)(logitsB + 4 * fN);
    ushort_t* e0b = hb + 128 * fN;
    ushort_t* e1b = e0b + 128 * fN;
    ushort_t* e2b = e1b + 128 * fN;
    ushort_t* e3b = e2b + 128 * fN;
    ushort_t* x0  = e3b + 128 * fN;
    ushort_t* x1  = x0 + 128 * fN;
    ushort_t* x2  = x1 + 128 * fN;
    ushort_t* x3  = x2 + 128 * fN;
    ushort_t* xm  = x3 + 128 * fN;
    ushort_t* xg1 = xm + 128 * fN;
    ushort_t* skb = xg1 + 128 * fN;
    ushort_t* qb  = skb + 128 * fN;
    ushort_t* kvb = qb + 128 * fN;           // 256N
    ushort_t* hrb = kvb + 256 * fN;          // 256N bf16 (router features)
    ushort_t* wt  = hrb + 256 * fN;
    WtPack wp;
    const float* wsrc[NWT] = {
        W[4], W[8], W[12], W[17], W[19],
        W[21], W[21] + 16384, W[21] + 32768, W[21] + 49152,
        W[23], W[25], W[27], W[29],                                     // q1,k1,v1,s1 (contiguous 512)
        W[23] + 16384, W[25] + 16384, W[27] + 16384, W[29] + 16384,     // q2,k2,v2,s2
        W[31], W[31] + 16384
    };
    const int wk[NWT] = {200, 128, 256, 128, 128,
                         128, 128, 128, 128,
                         128, 128, 128, 128,
                         128, 128, 128, 128,
                         128, 128};
    unsigned long long woff[NWT];
    unsigned long long acc_off = 0;
    for (int i = 0; i < NWT; i++) {
        wp.src[i] = wsrc[i];
        wp.K[i] = wk[i];
        wp.off[i] = acc_off;
        woff[i] = acc_off;
        acc_off += (unsigned long long)128 * wk[i];
    }
    int* degi   = (int*)(wt + acc_off + 8);
    int* cursor = degi + N;
    int* rowptr = cursor + N;
    int* csr    = rowptr + (N + 1);
    int* bstart = csr + E;
    int* bend   = bstart + B;
    int* bsum   = bend + B;
    float* ecA  = (float*)(bsum + 256);      // E floats (CSR-ordered sym-norm coefs)
    float* ecB  = ecA + E;                   // E floats (CSR-ordered GCN coefs)

    dim3 blk(256);
    int gN4 = (N + 3) / 4;
    int gG = (N + 63) / 64;
    int RT = (N + 15) / 16;
    int nsb = (N + SCH - 1) / SCH;
    int nseg = (N + 255) / 256;
    int nedge = (E + 255) / 256;
    int npool = B * (PCH / 4);

    // zero degi+cursor and bstart+bend (stream-ordered, graph-capturable)
    hipMemsetAsync(degi, 0, (size_t)2 * N * sizeof(int), stream);
    hipMemsetAsync(bstart, 0, (size_t)2 * B * sizeof(int), stream);

    // L0: wconv + seg_bounds + edge_deg
    setup_mega_kernel<<<dim3(608 + nseg + nedge), blk, 0, stream>>>(
        wp, wt, batch, bstart, bend, N, dst, degi, E);
    // L1/L2: scan phases
    scan1_kernel<<<dim3(nsb), blk, 0, stream>>>(degi, rowptr, bsum, N);
    scan2_kernel<<<1, blk, 0, stream>>>(bsum, nsb);
    // L3: scan3 + both encoder GEMMs (independent)
    EncCfg c0 = {W[0], 200, 200, wt + woff[0], hrb, W[5], W[6], W[7], W[16], logitsA};
    EncCfg c1 = {W[1], 128, 128, wt + woff[1], hrb + 128, W[9], W[10], W[11], W[16] + 512, logitsB};
    scan3_enc_kernel<<<dim3(nseg + 2 * gG), blk, 0, stream>>>(
        rowptr, bsum, degi, dinv, dinvl, N, c0, c1);
    // L4: fuse GEMM (K=256)+LN+ReLU -> hb  ||  csr_fill  ||  router top-k
    ln_csr_topk_kernel<<<dim3(gG + nedge + nseg), blk, 0, stream>>>(
        hrb, wt + woff[2], hb, N, W[13], W[14], W[15],
        src, dst, rowptr, cursor, csr, dinv, dinvl, ecA, ecB, E,
        logitsA, logitsB, gates);
    // L5: gather2 + MLP-L1 (both read hb only)
    flatA_kernel<<<dim3(gN4 + RT), blk, 0, stream>>>(hb, x1, x2, rowptr, csr, ecA, ecB,
                                                     dinvl, N, wt + woff[3], xm, W[18]);
    // L6: Q/K/V/S panels (layer1) + Cheb dual1 + GCN1
    megaA_kernel<<<dim3(gG, 6), blk, 0, stream>>>(
        hb, wt + woff[9], qb, kvb, skb, W[24], W[26], W[28], W[30],
        x1, wt + woff[5], wt + woff[6], x0, W[22],
        x2, wt + woff[17], xg1, W[32], N);
    // L7: attn1 + gather_l2
    flatB_kernel<<<dim3(2 * gN4), blk, 0, stream>>>(
        qb, kvb, rowptr, csr, skb, x1,
        x0, xg1, x3, x2, ecA, ecB, dinvl, N);
    // L8: QKVS2 panels + Cheb dual2 + GCN2 + MLP-L2
    megaB_kernel<<<dim3(gG, 7), blk, 0, stream>>>(
        x1, wt + woff[13], qb, kvb, skb,
        W[24] + 128, W[26] + 128, W[28] + 128, W[30] + 128,
        x0, wt + woff[7], x3, wt + woff[8], e1b, W[22] + 128,
        x2, wt + woff[18], e3b, W[32] + 128,
        xm, wt + woff[4], e0b, W[20], N);
    // L9: attn2 -> e2b  ||  poolA (h, e0, e1, e3)
    attn2_pool_kernel<<<dim3(gN4 + npool), blk, 0, stream>>>(
        qb, kvb, rowptr, csr, skb, e2b, N,
        hb, e0b, e1b, e3b, gates, W[33], W[34], W[35], bstart, bend, partial);
    // L10: poolB (e2) -> partial2
    poolB_kernel<<<dim3(npool), blk, 0, stream>>>(
        e2b, gates, W[33], W[34], W[35], bstart, bend, partial2);
    // L11: head
    head_kernel<<<dim3(B), dim3(128), 0, stream>>>(partial, partial2, bstart, bend,
        W[36], W[37], W[38], W[39],
        W[40], W[41], W[42], W[43],
        W[44], W[45], W[46],
        (float*)d_out, B);
}

// Round 11
// 485.619 us; speedup vs baseline: 1.0656x; 1.0258x over previous
//
#include <hip/hip_runtime.h>

#define PCH   32
#define NWT   19
#define SCH   2048

typedef unsigned short ushort_t;
typedef __attribute__((ext_vector_type(8))) short bf16x8;
typedef __attribute__((ext_vector_type(4))) float f32x4;

__device__ __forceinline__ float bf2f(unsigned int v) {
    return __uint_as_float(v << 16);
}
__device__ __forceinline__ unsigned int f2bu(float f) {
    unsigned int u = __float_as_uint(f);
    return (u + 0x7fffu + ((u >> 16) & 1u)) >> 16;
}
__device__ __forceinline__ void unpack8(uint4 u, float* f) {
    f[0] = bf2f(u.x & 0xffff); f[1] = bf2f(u.x >> 16);
    f[2] = bf2f(u.y & 0xffff); f[3] = bf2f(u.y >> 16);
    f[4] = bf2f(u.z & 0xffff); f[5] = bf2f(u.z >> 16);
    f[6] = bf2f(u.w & 0xffff); f[7] = bf2f(u.w >> 16);
}
__device__ __forceinline__ uint4 pack8(const float* f) {
    uint4 p;
    p.x = f2bu(f[0]) | (f2bu(f[1]) << 16);
    p.y = f2bu(f[2]) | (f2bu(f[3]) << 16);
    p.z = f2bu(f[4]) | (f2bu(f[5]) << 16);
    p.w = f2bu(f[6]) | (f2bu(f[7]) << 16);
    return p;
}
__device__ __forceinline__ void fma8(uint4 u, float c, float* a) {
    a[0] = fmaf(c, bf2f(u.x & 0xffff), a[0]);
    a[1] = fmaf(c, bf2f(u.x >> 16), a[1]);
    a[2] = fmaf(c, bf2f(u.y & 0xffff), a[2]);
    a[3] = fmaf(c, bf2f(u.y >> 16), a[3]);
    a[4] = fmaf(c, bf2f(u.z & 0xffff), a[4]);
    a[5] = fmaf(c, bf2f(u.z >> 16), a[5]);
    a[6] = fmaf(c, bf2f(u.w & 0xffff), a[6]);
    a[7] = fmaf(c, bf2f(u.w >> 16), a[7]);
}
__device__ __forceinline__ float dot8(uint4 u, const float* q) {
    float d = q[0] * bf2f(u.x & 0xffff);
    d = fmaf(q[1], bf2f(u.x >> 16), d);
    d = fmaf(q[2], bf2f(u.y & 0xffff), d);
    d = fmaf(q[3], bf2f(u.y >> 16), d);
    d = fmaf(q[4], bf2f(u.z & 0xffff), d);
    d = fmaf(q[5], bf2f(u.z >> 16), d);
    d = fmaf(q[6], bf2f(u.w & 0xffff), d);
    d = fmaf(q[7], bf2f(u.w >> 16), d);
    return d;
}

struct WtPack {
    const float* src[NWT];
    unsigned long long off[NWT];
    int K[NWT];
};

// ---------------- merged setup: wconv + seg_bounds + edge_deg ----------------
__global__ void setup_mega_kernel(WtPack p, ushort_t* __restrict__ base,
                                  const int* __restrict__ batch,
                                  int* __restrict__ bstart, int* __restrict__ bend, int N,
                                  const int* __restrict__ dst, int* __restrict__ degi, int E)
{
    int bx = blockIdx.x, tid = threadIdx.x;
    int nseg = (N + 255) >> 8;
    if (bx < 608) {
        int a = bx >> 5, xp = bx & 31;
        const float* s = p.src[a];
        ushort_t* d = base + p.off[a];
        int K = p.K[a];
        int total = K * 128;
        for (int i = xp * 256 + tid; i < total; i += 32 * 256) {
            int k = i >> 7, n = i & 127;
            d[n * K + k] = (ushort_t)f2bu(s[i]);
        }
    } else if (bx < 608 + nseg) {
        int n = (bx - 608) * 256 + tid;
        if (n >= N) return;
        int b = batch[n];
        if (n == 0) bstart[b] = 0;
        else {
            int pb = batch[n - 1];
            if (pb != b) { bstart[b] = n; bend[pb] = n; }
        }
        if (n == N - 1) bend[b] = N;
    } else {
        int e = (bx - 608 - nseg) * 256 + tid;
        if (e < E) atomicAdd(&degi[dst[e]], 1);
    }
}

// ---------- parallel 3-phase scan ----------
__global__ void scan1_kernel(const int* __restrict__ degi, int* __restrict__ rowptr,
                             int* __restrict__ bsum, int n) {
    __shared__ int sh[256];
    int tid = threadIdx.x;
    int base = blockIdx.x * SCH + tid * 8;
    int loc[8]; int s = 0;
#pragma unroll
    for (int j = 0; j < 8; j++) {
        int idx = base + j;
        int v = (idx < n) ? degi[idx] : 0;
        s += v; loc[j] = s;
    }
    sh[tid] = s;
    __syncthreads();
    for (int off = 1; off < 256; off <<= 1) {
        int t = (tid >= off) ? sh[tid - off] : 0;
        __syncthreads();
        sh[tid] += t;
        __syncthreads();
    }
    int prev = (tid > 0) ? sh[tid - 1] : 0;
#pragma unroll
    for (int j = 0; j < 8; j++) {
        int idx = base + j;
        if (idx < n) rowptr[idx + 1] = prev + loc[j];
    }
    if (tid == 255) bsum[blockIdx.x] = sh[255];
}
__global__ void scan2_kernel(int* __restrict__ bsum, int nb) {
    __shared__ int sh[256];
    int tid = threadIdx.x;
    sh[tid] = (tid < nb) ? bsum[tid] : 0;
    __syncthreads();
    for (int off = 1; off < 256; off <<= 1) {
        int t = (tid >= off) ? sh[tid - off] : 0;
        __syncthreads();
        sh[tid] += t;
        __syncthreads();
    }
    if (tid < nb) bsum[tid] = (tid > 0) ? sh[tid - 1] : 0;
}

// ---------- fp32-A MFMA GEMM + fused LN+ReLU + router partials (device) ----------
struct EncCfg {
    const float* A; int lda; int K;
    const ushort_t* Wt; ushort_t* Cb;           // Cb stride 256
    const float* bias; const float* g; const float* be;
    const float* rW; float* logits;
};

__device__ __forceinline__ void gemm_f32_ln_dev(ushort_t (*As)[40], ushort_t (*Bs)[40],
                                                const EncCfg c, int bx, int M)
{
    const int tid = threadIdx.x;
    const int m0 = bx * 64;
    const int lane = tid & 63;
    const int wv = tid >> 6;
    const int q = lane >> 4;
    const int l16 = lane & 15;
    const int sar = tid >> 2;
    const int sak = (tid & 3) << 3;
    const int sbn = tid >> 1;
    const int sbk = (tid & 1) << 4;
    const int K = c.K;
    const bool arow_ok = (m0 + sar) < M;
    const float* Arow = c.A + (size_t)(m0 + sar) * c.lda;
    const ushort_t* Wrow = c.Wt + (size_t)sbn * K;

    f32x4 acc[8];
#pragma unroll
    for (int t = 0; t < 8; t++) acc[t] = (f32x4){0.f, 0.f, 0.f, 0.f};

    for (int k0 = 0; k0 < K; k0 += 32) {
        uint4 apk;
        if (arow_ok && k0 + sak + 8 <= K) {
            float4 p0 = *(const float4*)(Arow + k0 + sak);
            float4 p1 = *(const float4*)(Arow + k0 + sak + 4);
            apk.x = f2bu(p0.x) | (f2bu(p0.y) << 16);
            apk.y = f2bu(p0.z) | (f2bu(p0.w) << 16);
            apk.z = f2bu(p1.x) | (f2bu(p1.y) << 16);
            apk.w = f2bu(p1.z) | (f2bu(p1.w) << 16);
        } else {
            unsigned int t4[4] = {0, 0, 0, 0};
            for (int j = 0; j < 8; j++) {
                int k = k0 + sak + j;
                unsigned int bv = (arow_ok && k < K) ? f2bu(Arow[k]) : 0u;
                t4[j >> 1] |= bv << ((j & 1) * 16);
            }
            apk = make_uint4(t4[0], t4[1], t4[2], t4[3]);
        }
        uint4 b0, b1;
        if (k0 + sbk + 16 <= K) {
            b0 = *(const uint4*)(Wrow + k0 + sbk);
            b1 = *(const uint4*)(Wrow + k0 + sbk + 8);
        } else {
            unsigned int t8[8] = {0, 0, 0, 0, 0, 0, 0, 0};
            for (int j = 0; j < 16; j++) {
                int k = k0 + sbk + j;
                unsigned int bv = (k < K) ? (unsigned int)Wrow[k] : 0u;
                t8[j >> 1] |= bv << ((j & 1) * 16);
            }
            b0 = make_uint4(t8[0], t8[1], t8[2], t8[3]);
            b1 = make_uint4(t8[4], t8[5], t8[6], t8[7]);
        }
        __syncthreads();
        *(uint4*)&As[sar][sak] = apk;
        *(uint4*)&Bs[sbn][sbk] = b0;
        *(uint4*)&Bs[sbn][sbk + 8] = b1;
        __syncthreads();
        bf16x8 af = *(const bf16x8*)&As[16 * wv + l16][q * 8];
#pragma unroll
        for (int t = 0; t < 8; t++) {
            bf16x8 bf = *(const bf16x8*)&Bs[t * 16 + l16][q * 8];
            acc[t] = __builtin_amdgcn_mfma_f32_16x16x32_bf16(af, bf, acc[t], 0, 0, 0);
        }
    }
    const int row_base = m0 + 16 * wv + q * 4;
#pragma unroll
    for (int t = 0; t < 8; t++) {
        float bb = c.bias[t * 16 + l16];
#pragma unroll
        for (int r = 0; r < 4; r++) acc[t][r] += bb;
    }
    float mean[4], inv[4];
#pragma unroll
    for (int r = 0; r < 4; r++) {
        float s = 0.f, sq = 0.f;
#pragma unroll
        for (int t = 0; t < 8; t++) { float v = acc[t][r]; s += v; sq = fmaf(v, v, sq); }
#pragma unroll
        for (int off = 1; off <= 8; off <<= 1) { s += __shfl_xor(s, off); sq += __shfl_xor(sq, off); }
        mean[r] = s * (1.f / 128.f);
        float var = sq * (1.f / 128.f) - mean[r] * mean[r];
        inv[r] = rsqrtf(var + 1e-5f);
    }
    float rl0[4] = {0, 0, 0, 0}, rl1[4] = {0, 0, 0, 0};
    float rl2[4] = {0, 0, 0, 0}, rl3[4] = {0, 0, 0, 0};
#pragma unroll
    for (int t = 0; t < 8; t++) {
        int col = t * 16 + l16;
        float gg = c.g[col], b2 = c.be[col];
        float4 rw = *(const float4*)(c.rW + col * 4);
#pragma unroll
        for (int r = 0; r < 4; r++) {
            float y = fmaxf(fmaf((acc[t][r] - mean[r]) * inv[r], gg, b2), 0.f);
            rl0[r] = fmaf(y, rw.x, rl0[r]);
            rl1[r] = fmaf(y, rw.y, rl1[r]);
            rl2[r] = fmaf(y, rw.z, rl2[r]);
            rl3[r] = fmaf(y, rw.w, rl3[r]);
            float other = __shfl_xor(y, 1);
            int row = row_base + r;
            if (!(l16 & 1) && row < M) {
                unsigned int pk = f2bu(y) | (f2bu(other) << 16);
                *(unsigned int*)(c.Cb + (size_t)row * 256 + col) = pk;
            }
        }
    }
#pragma unroll
    for (int r = 0; r < 4; r++) {
#pragma unroll
        for (int off = 1; off <= 8; off <<= 1) {
            rl0[r] += __shfl_xor(rl0[r], off);
            rl1[r] += __shfl_xor(rl1[r], off);
            rl2[r] += __shfl_xor(rl2[r], off);
            rl3[r] += __shfl_xor(rl3[r], off);
        }
        int row = row_base + r;
        if (l16 == 0 && row < M)
            *(float4*)(c.logits + (size_t)row * 4) = make_float4(rl0[r], rl1[r], rl2[r], rl3[r]);
    }
}

// ---------- merged scan3 + encoder GEMMs ----------
__global__ __launch_bounds__(256)
void scan3_enc_kernel(int* __restrict__ rowptr, const int* __restrict__ bsum,
                      const int* __restrict__ degi,
                      float* __restrict__ dinv, float* __restrict__ dinvl, int N,
                      EncCfg c0, EncCfg c1)
{
    __shared__ ushort_t As[64][40];
    __shared__ ushort_t Bs[128][40];
    int bx = blockIdx.x;
    int ns3 = (N + 255) >> 8;
    int gG = (N + 63) >> 6;
    if (bx < ns3) {
        int i = bx * 256 + threadIdx.x;
        if (i == 0) rowptr[0] = 0;
        if (i < N) {
            rowptr[i + 1] += bsum[i / SCH];
            float deg = (float)degi[i];
            dinv[i] = (deg > 0.f) ? rsqrtf(fmaxf(deg, 1.f)) : 0.f;
            dinvl[i] = rsqrtf(deg + 1.f);
        }
        return;
    }
    int b2 = bx - ns3;
    if (b2 < gG) gemm_f32_ln_dev(As, Bs, c0, b2, N);
    else gemm_f32_ln_dev(As, Bs, c1, b2 - gG, N);
}

// ---------- device: fuse GEMM K=256 with LN+ReLU epilogue ----------
__device__ __forceinline__ void gemm_ln256_dev(ushort_t (*As)[40], ushort_t (*Bs)[40],
                                               const ushort_t* __restrict__ A,
                                               const ushort_t* __restrict__ Wt,
                                               ushort_t* __restrict__ Cb, int M,
                                               const float* __restrict__ bias,
                                               const float* __restrict__ g,
                                               const float* __restrict__ be, int bx)
{
    const int K = 256;
    const int tid = threadIdx.x;
    const int m0 = bx * 64;
    const int lane = tid & 63;
    const int wv = tid >> 6;
    const int q = lane >> 4;
    const int l16 = lane & 15;
    const int sar = tid >> 2;
    const int sak = (tid & 3) << 3;
    const int sbn = tid >> 1;
    const int sbk = (tid & 1) << 4;
    const bool arow_ok = (m0 + sar) < M;
    const ushort_t* Arow = A + (size_t)(m0 + sar) * K;
    const ushort_t* Wrow = Wt + (size_t)sbn * K;

    f32x4 acc[8];
#pragma unroll
    for (int t = 0; t < 8; t++) acc[t] = (f32x4){0.f, 0.f, 0.f, 0.f};

#pragma unroll
    for (int k0 = 0; k0 < K; k0 += 32) {
        uint4 apk = arow_ok ? *(const uint4*)(Arow + k0 + sak) : make_uint4(0, 0, 0, 0);
        uint4 b0 = *(const uint4*)(Wrow + k0 + sbk);
        uint4 b1 = *(const uint4*)(Wrow + k0 + sbk + 8);
        __syncthreads();
        *(uint4*)&As[sar][sak] = apk;
        *(uint4*)&Bs[sbn][sbk] = b0;
        *(uint4*)&Bs[sbn][sbk + 8] = b1;
        __syncthreads();
        bf16x8 af = *(const bf16x8*)&As[16 * wv + l16][q * 8];
#pragma unroll
        for (int t = 0; t < 8; t++) {
            bf16x8 bf = *(const bf16x8*)&Bs[t * 16 + l16][q * 8];
            acc[t] = __builtin_amdgcn_mfma_f32_16x16x32_bf16(af, bf, acc[t], 0, 0, 0);
        }
    }
    const int row_base = m0 + 16 * wv + q * 4;
#pragma unroll
    for (int t = 0; t < 8; t++) {
        float bb = bias[t * 16 + l16];
#pragma unroll
        for (int r = 0; r < 4; r++) acc[t][r] += bb;
    }
    float mean[4], inv[4];
#pragma unroll
    for (int r = 0; r < 4; r++) {
        float s = 0.f, sq = 0.f;
#pragma unroll
        for (int t = 0; t < 8; t++) { float v = acc[t][r]; s += v; sq = fmaf(v, v, sq); }
#pragma unroll
        for (int off = 1; off <= 8; off <<= 1) { s += __shfl_xor(s, off); sq += __shfl_xor(sq, off); }
        mean[r] = s * (1.f / 128.f);
        float var = sq * (1.f / 128.f) - mean[r] * mean[r];
        inv[r] = rsqrtf(var + 1e-5f);
    }
#pragma unroll
    for (int t = 0; t < 8; t++) {
        int col = t * 16 + l16;
        float gg = g[col], b2 = be[col];
#pragma unroll
        for (int r = 0; r < 4; r++) {
            float y = fmaxf(fmaf((acc[t][r] - mean[r]) * inv[r], gg, b2), 0.f);
            float other = __shfl_xor(y, 1);
            int row = row_base + r;
            if (!(l16 & 1) && row < M) {
                unsigned int pk = f2bu(y) | (f2bu(other) << 16);
                *(unsigned int*)(Cb + (size_t)row * 128 + col) = pk;
            }
        }
    }
}

// ---------- merged: fuse GEMM + csr_fill + router top-k ----------
__global__ __launch_bounds__(256)
void ln_csr_topk_kernel(const ushort_t* __restrict__ A, const ushort_t* __restrict__ Wt,
                        ushort_t* __restrict__ Cb, int N,
                        const float* __restrict__ bias,
                        const float* __restrict__ g, const float* __restrict__ be,
                        const int* __restrict__ src, const int* __restrict__ dst,
                        const int* __restrict__ rowptr, int* __restrict__ cursor,
                        int* __restrict__ csr,
                        const float* __restrict__ dinv, const float* __restrict__ dinvl,
                        float* __restrict__ ecA, float* __restrict__ ecB, int E,
                        const float* __restrict__ la, const float* __restrict__ lb,
                        float* __restrict__ gates)
{
    __shared__ ushort_t As[64][40];
    __shared__ ushort_t Bs[128][40];
    int bx = blockIdx.x;
    int gG = (N + 63) >> 6;
    int nedge = (E + 255) >> 8;
    if (bx < gG) {
        gemm_ln256_dev(As, Bs, A, Wt, Cb, N, bias, g, be, bx);
        return;
    }
    if (bx < gG + nedge) {
        int e = (bx - gG) * 256 + threadIdx.x;
        if (e >= E) return;
        int d = dst[e];
        int s = src[e];
        int pos = atomicAdd(&cursor[d], 1);
        int o = rowptr[d] + pos;
        csr[o] = s;
        ecA[o] = dinv[d] * dinv[s];
        ecB[o] = dinvl[d] * dinvl[s];
        return;
    }
    int n = (bx - gG - nedge) * 256 + threadIdx.x;
    if (n >= N) return;
    float4 a = *(const float4*)(la + (size_t)n * 4);
    float4 b = *(const float4*)(lb + (size_t)n * 4);
    float l[4] = {(a.x + b.x) * (1.f / 1.5f), (a.y + b.y) * (1.f / 1.5f),
                  (a.z + b.z) * (1.f / 1.5f), (a.w + b.w) * (1.f / 1.5f)};
    float mx = fmaxf(fmaxf(l[0], l[1]), fmaxf(l[2], l[3]));
    float e4[4], ssum = 0.f;
#pragma unroll
    for (int i = 0; i < 4; i++) { e4[i] = expf(l[i] - mx); ssum += e4[i]; }
    float p[4];
#pragma unroll
    for (int i = 0; i < 4; i++) p[i] = e4[i] / ssum;
    int i0 = 0;
    for (int i = 1; i < 4; i++) if (p[i] > p[i0]) i0 = i;
    int i1 = -1;
    for (int i = 0; i < 4; i++) {
        if (i == i0) continue;
        if (i1 < 0 || p[i] > p[i1]) i1 = i;
    }
    float wsum = fmaxf(p[i0] + p[i1], 1e-9f);
    float gg[4] = {0.f, 0.f, 0.f, 0.f};
    gg[i0] = p[i0] / wsum;
    gg[i1] = p[i1] / wsum;
    *(float4*)(gates + (size_t)n * 4) = make_float4(gg[0], gg[1], gg[2], gg[3]);
}

// ---------- device: bf16 LDS GEMM (K templated), plain epilogue ----------
template <int K>
__device__ __forceinline__ void gemm_bf_dev(ushort_t (*As)[40], ushort_t (*Bs)[40],
                                            const ushort_t* __restrict__ A,
                                            const ushort_t* __restrict__ Wt,
                                            ushort_t* __restrict__ Cb, int M,
                                            const float* __restrict__ bias, int relu, int bx)
{
    const int tid = threadIdx.x;
    const int m0 = bx * 64;
    const int lane = tid & 63;
    const int wv = tid >> 6;
    const int q = lane >> 4;
    const int l16 = lane & 15;
    const int sar = tid >> 2;
    const int sak = (tid & 3) << 3;
    const int sbn = tid >> 1;
    const int sbk = (tid & 1) << 4;
    const bool arow_ok = (m0 + sar) < M;
    const ushort_t* Arow = A + (size_t)(m0 + sar) * K;
    const ushort_t* Wrow = Wt + (size_t)sbn * K;

    f32x4 acc[8];
#pragma unroll
    for (int t = 0; t < 8; t++) acc[t] = (f32x4){0.f, 0.f, 0.f, 0.f};

#pragma unroll
    for (int k0 = 0; k0 < K; k0 += 32) {
        uint4 apk = arow_ok ? *(const uint4*)(Arow + k0 + sak) : make_uint4(0, 0, 0, 0);
        uint4 b0 = *(const uint4*)(Wrow + k0 + sbk);
        uint4 b1 = *(const uint4*)(Wrow + k0 + sbk + 8);
        __syncthreads();
        *(uint4*)&As[sar][sak] = apk;
        *(uint4*)&Bs[sbn][sbk] = b0;
        *(uint4*)&Bs[sbn][sbk + 8] = b1;
        __syncthreads();
        bf16x8 af = *(const bf16x8*)&As[16 * wv + l16][q * 8];
#pragma unroll
        for (int t = 0; t < 8; t++) {
            bf16x8 bf = *(const bf16x8*)&Bs[t * 16 + l16][q * 8];
            acc[t] = __builtin_amdgcn_mfma_f32_16x16x32_bf16(af, bf, acc[t], 0, 0, 0);
        }
    }
#pragma unroll
    for (int t = 0; t < 8; t++) {
        int col = t * 16 + l16;
        float bb = bias ? bias[col] : 0.f;
#pragma unroll
        for (int r = 0; r < 4; r++) {
            int row = m0 + 16 * wv + q * 4 + r;
            float val = acc[t][r] + bb;
            if (relu) val = fmaxf(val, 0.f);
            float other = __shfl_xor(val, 1);
            if (!(lane & 1) && row < M) {
                unsigned int pk = f2bu(val) | (f2bu(other) << 16);
                *(unsigned int*)(Cb + (size_t)row * 128 + col) = pk;
            }
        }
    }
}

// ---------- device: bf16 LDS GEMM with output stride (K=128), plain bias ----------
__device__ __forceinline__ void gemm_bfs_dev(ushort_t (*As)[40], ushort_t (*Bs)[40],
                                             const ushort_t* __restrict__ A,
                                             const ushort_t* __restrict__ Wt,
                                             ushort_t* __restrict__ Cb, int ldc, int M,
                                             const float* __restrict__ bias, int bx)
{
    const int K = 128;
    const int tid = threadIdx.x;
    const int m0 = bx * 64;
    const int lane = tid & 63;
    const int wv = tid >> 6;
    const int q = lane >> 4;
    const int l16 = lane & 15;
    const int sar = tid >> 2;
    const int sak = (tid & 3) << 3;
    const int sbn = tid >> 1;
    const int sbk = (tid & 1) << 4;
    const bool arow_ok = (m0 + sar) < M;
    const ushort_t* Arow = A + (size_t)(m0 + sar) * K;
    const ushort_t* Wrow = Wt + (size_t)sbn * K;

    f32x4 acc[8];
#pragma unroll
    for (int t = 0; t < 8; t++) acc[t] = (f32x4){0.f, 0.f, 0.f, 0.f};

#pragma unroll
    for (int k0 = 0; k0 < K; k0 += 32) {
        uint4 apk = arow_ok ? *(const uint4*)(Arow + k0 + sak) : make_uint4(0, 0, 0, 0);
        uint4 b0 = *(const uint4*)(Wrow + k0 + sbk);
        uint4 b1 = *(const uint4*)(Wrow + k0 + sbk + 8);
        __syncthreads();
        *(uint4*)&As[sar][sak] = apk;
        *(uint4*)&Bs[sbn][sbk] = b0;
        *(uint4*)&Bs[sbn][sbk + 8] = b1;
        __syncthreads();
        bf16x8 af = *(const bf16x8*)&As[16 * wv + l16][q * 8];
#pragma unroll
        for (int t = 0; t < 8; t++) {
            bf16x8 bf = *(const bf16x8*)&Bs[t * 16 + l16][q * 8];
            acc[t] = __builtin_amdgcn_mfma_f32_16x16x32_bf16(af, bf, acc[t], 0, 0, 0);
        }
    }
#pragma unroll
    for (int t = 0; t < 8; t++) {
        int col = t * 16 + l16;
        float bb = bias[col];
#pragma unroll
        for (int r = 0; r < 4; r++) {
            int row = m0 + 16 * wv + q * 4 + r;
            float val = acc[t][r] + bb;
            float other = __shfl_xor(val, 1);
            if (!(lane & 1) && row < M) {
                unsigned int pk = f2bu(val) | (f2bu(other) << 16);
                *(unsigned int*)(Cb + (size_t)row * ldc + col) = pk;
            }
        }
    }
}

// ---------- device: dual GEMM C = A1@W1 + A2@W2 ----------
__device__ __forceinline__ void gemm_dual_dev(ushort_t (*As)[40], ushort_t (*Bs)[40],
                                              const ushort_t* __restrict__ A1,
                                              const ushort_t* __restrict__ Wt1,
                                              const ushort_t* __restrict__ A2,
                                              const ushort_t* __restrict__ Wt2,
                                              ushort_t* __restrict__ Cb, int M,
                                              const float* __restrict__ bias, int relu, int bx)
{
    const int K = 128;
    const int tid = threadIdx.x;
    const int m0 = bx * 64;
    const int lane = tid & 63;
    const int wv = tid >> 6;
    const int q = lane >> 4;
    const int l16 = lane & 15;
    const int sar = tid >> 2;
    const int sak = (tid & 3) << 3;
    const int sbn = tid >> 1;
    const int sbk = (tid & 1) << 4;
    const bool arow_ok = (m0 + sar) < M;

    f32x4 acc[8];
#pragma unroll
    for (int t = 0; t < 8; t++) acc[t] = (f32x4){0.f, 0.f, 0.f, 0.f};

    for (int ph = 0; ph < 2; ph++) {
        const ushort_t* Arow = (ph ? A2 : A1) + (size_t)(m0 + sar) * K;
        const ushort_t* Wrow = (ph ? Wt2 : Wt1) + (size_t)sbn * K;
        for (int k0 = 0; k0 < K; k0 += 32) {
            uint4 apk = arow_ok ? *(const uint4*)(Arow + k0 + sak) : make_uint4(0, 0, 0, 0);
            uint4 b0 = *(const uint4*)(Wrow + k0 + sbk);
            uint4 b1 = *(const uint4*)(Wrow + k0 + sbk + 8);
            __syncthreads();
            *(uint4*)&As[sar][sak] = apk;
            *(uint4*)&Bs[sbn][sbk] = b0;
            *(uint4*)&Bs[sbn][sbk + 8] = b1;
            __syncthreads();
            bf16x8 af = *(const bf16x8*)&As[16 * wv + l16][q * 8];
#pragma unroll
            for (int t = 0; t < 8; t++) {
                bf16x8 bf = *(const bf16x8*)&Bs[t * 16 + l16][q * 8];
                acc[t] = __builtin_amdgcn_mfma_f32_16x16x32_bf16(af, bf, acc[t], 0, 0, 0);
            }
        }
    }
#pragma unroll
    for (int t = 0; t < 8; t++) {
        int col = t * 16 + l16;
        float bb = bias ? bias[col] : 0.f;
#pragma unroll
        for (int r = 0; r < 4; r++) {
            int row = m0 + 16 * wv + q * 4 + r;
            float val = acc[t][r] + bb;
            if (relu) val = fmaxf(val, 0.f);
            float other = __shfl_xor(val, 1);
            if (!(lane & 1) && row < M) {
                unsigned int pk = f2bu(val) | (f2bu(other) << 16);
                *(unsigned int*)(Cb + (size_t)row * 128 + col) = pk;
            }
        }
    }
}

// ---------- device: no-LDS wave-tile GEMM (K=128, col-split 4) ----------
__device__ __forceinline__ void gemm_wv_dev(const ushort_t* __restrict__ A,
                                            const ushort_t* __restrict__ Wt,
                                            ushort_t* __restrict__ Cb, int M,
                                            const float* __restrict__ bias, int relu,
                                            int w, int lane)
{
    const int K = 128;
    int ct = w & 3;
    int rt = w >> 2;
    int row0 = rt * 16;
    if (row0 >= M) return;
    int l16 = lane & 15, q = lane >> 4;
    int arow = row0 + l16;
    bool aok = arow < M;
    const ushort_t* Ar = A + (size_t)arow * K + q * 8;
    const ushort_t* W0 = Wt + (size_t)(ct * 32 + l16) * K + q * 8;
    const ushort_t* W1 = W0 + (size_t)16 * K;
    bf16x8 zz = {0, 0, 0, 0, 0, 0, 0, 0};
    f32x4 a0 = {0.f, 0.f, 0.f, 0.f}, a1 = {0.f, 0.f, 0.f, 0.f};
#pragma unroll
    for (int k0 = 0; k0 < K; k0 += 32) {
        bf16x8 af = aok ? *(const bf16x8*)(Ar + k0) : zz;
        bf16x8 b0 = *(const bf16x8*)(W0 + k0);
        bf16x8 b1 = *(const bf16x8*)(W1 + k0);
        a0 = __builtin_amdgcn_mfma_f32_16x16x32_bf16(af, b0, a0, 0, 0, 0);
        a1 = __builtin_amdgcn_mfma_f32_16x16x32_bf16(af, b1, a1, 0, 0, 0);
    }
    f32x4 av[2] = {a0, a1};
#pragma unroll
    for (int t = 0; t < 2; t++) {
        int col = ct * 32 + t * 16 + l16;
        float bb = bias ? bias[col] : 0.f;
#pragma unroll
        for (int r = 0; r < 4; r++) {
            int row = row0 + q * 4 + r;
            float val = av[t][r] + bb;
            if (relu) val = fmaxf(val, 0.f);
            float other = __shfl_xor(val, 1);
            if (!(l16 & 1) && row < M) {
                unsigned int pk = f2bu(val) | (f2bu(other) << 16);
                *(unsigned int*)(Cb + (size_t)row * 128 + col) = pk;
            }
        }
    }
}

// ---------- device: dual gather layer-1 (software-pipelined rows) ----------
__device__ __forceinline__ void gather2_dev(const ushort_t* __restrict__ Xb,
                                            ushort_t* __restrict__ OutA, ushort_t* __restrict__ OutB,
                                            const int* __restrict__ rowptr, const int* __restrict__ csr,
                                            const float* __restrict__ ecA, const float* __restrict__ ecB,
                                            const float* __restrict__ dinvl, int M, int bx)
{
    int node = bx * 4 + (threadIdx.x >> 6);
    int lane = threadIdx.x & 63;
    if (node >= M) return;
    int beg = rowptr[node], end = rowptr[node + 1];
    int slot = lane >> 4, g = lane & 15;
    float aA[8] = {0, 0, 0, 0, 0, 0, 0, 0};
    float aB[8] = {0, 0, 0, 0, 0, 0, 0, 0};

    float cAa = 0.f, cBa = 0.f, cAb = 0.f, cBb = 0.f;
    int na = 0, nb = 0;
    float nAa = 0.f, nBa = 0.f, nAb = 0.f, nBb = 0.f;
    uint4 xA, xB;
    {
        int r0 = beg + slot, r1 = beg + 4 + slot;
        int ia = 0, ib = 0;
        if (r0 < end) { ia = csr[r0]; cAa = ecA[r0]; cBa = ecB[r0]; }
        if (r1 < end) { ib = csr[r1]; cAb = ecA[r1]; cBb = ecB[r1]; }
        xA = *(const uint4*)(Xb + (size_t)ia * 128 + g * 8);
        xB = *(const uint4*)(Xb + (size_t)ib * 128 + g * 8);
    }
    {
        int r0 = beg + 8 + slot, r1 = beg + 12 + slot;
        if (r0 < end) { na = csr[r0]; nAa = ecA[r0]; nBa = ecB[r0]; }
        if (r1 < end) { nb = csr[r1]; nAb = ecA[r1]; nBb = ecB[r1]; }
    }
    for (int e = beg; e < end; e += 8) {
        uint4 xA2 = *(const uint4*)(Xb + (size_t)na * 128 + g * 8);
        uint4 xB2 = *(const uint4*)(Xb + (size_t)nb * 128 + g * 8);
        int r0 = e + 16 + slot, r1 = e + 20 + slot;
        int ma = 0, mb = 0;
        float mAa = 0.f, mBa = 0.f, mAb = 0.f, mBb = 0.f;
        if (r0 < end) { ma = csr[r0]; mAa = ecA[r0]; mBa = ecB[r0]; }
        if (r1 < end) { mb = csr[r1]; mAb = ecA[r1]; mBb = ecB[r1]; }
        fma8(xA, cAa, aA); fma8(xA, cBa, aB);
        fma8(xB, cAb, aA); fma8(xB, cBb, aB);
        xA = xA2; xB = xB2;
        cAa = nAa; cBa = nBa; cAb = nAb; cBb = nBb;
        na = ma; nb = mb;
        nAa = mAa; nBa = mBa; nAb = mAb; nBb = mBb;
    }
#pragma unroll
    for (int j = 0; j < 8; j++) {
        aA[j] += __shfl_xor(aA[j], 16); aA[j] += __shfl_xor(aA[j], 32);
        aB[j] += __shfl_xor(aB[j], 16); aB[j] += __shfl_xor(aB[j], 32);
    }
    {
        float c = dinvl[node]; c *= c;
        uint4 xs = *(const uint4*)(Xb + (size_t)node * 128 + g * 8);
        fma8(xs, c, aB);
    }
    if (lane < 16) {
        float oA[8], oB[8];
#pragma unroll
        for (int j = 0; j < 8; j++) { oA[j] = -aA[j]; oB[j] = aB[j]; }
        size_t ofs = (size_t)node * 128 + g * 8;
        *(uint4*)(OutA + ofs) = pack8(oA);
        *(uint4*)(OutB + ofs) = pack8(oB);
    }
}

// ---------- device: dual-input gather layer-2 (software-pipelined rows) ----------
__device__ __forceinline__ void gather_l2_dev(const ushort_t* __restrict__ XA,
                                              const ushort_t* __restrict__ XB,
                                              ushort_t* __restrict__ OutA, ushort_t* __restrict__ OutB,
                                              const int* __restrict__ rowptr, const int* __restrict__ csr,
                                              const float* __restrict__ ecA, const float* __restrict__ ecB,
                                              const float* __restrict__ dinvl, int M, int bx)
{
    int node = bx * 4 + (threadIdx.x >> 6);
    int lane = threadIdx.x & 63;
    if (node >= M) return;
    int beg = rowptr[node], end = rowptr[node + 1];
    int slot = lane >> 4, g = lane & 15;
    float aA[8] = {0, 0, 0, 0, 0, 0, 0, 0};
    float aB[8] = {0, 0, 0, 0, 0, 0, 0, 0};

    float cAa = 0.f, cBa = 0.f, cAb = 0.f, cBb = 0.f;
    int na = 0, nb = 0;
    float nAa = 0.f, nBa = 0.f, nAb = 0.f, nBb = 0.f;
    uint4 ra, rb, sa, sb;
    {
        int r0 = beg + slot, r1 = beg + 4 + slot;
        int ia = 0, ib = 0;
        if (r0 < end) { ia = csr[r0]; cAa = ecA[r0]; cBa = ecB[r0]; }
        if (r1 < end) { ib = csr[r1]; cAb = ecA[r1]; cBb = ecB[r1]; }
        ra = *(const uint4*)(XA + (size_t)ia * 128 + g * 8);
        rb = *(const uint4*)(XA + (size_t)ib * 128 + g * 8);
        sa = *(const uint4*)(XB + (size_t)ia * 128 + g * 8);
        sb = *(const uint4*)(XB + (size_t)ib * 128 + g * 8);
    }
    {
        int r0 = beg + 8 + slot, r1 = beg + 12 + slot;
        if (r0 < end) { na = csr[r0]; nAa = ecA[r0]; nBa = ecB[r0]; }
        if (r1 < end) { nb = csr[r1]; nAb = ecA[r1]; nBb = ecB[r1]; }
    }
    for (int e = beg; e < end; e += 8) {
        uint4 ra2 = *(const uint4*)(XA + (size_t)na * 128 + g * 8);
        uint4 rb2 = *(const uint4*)(XA + (size_t)nb * 128 + g * 8);
        uint4 sa2 = *(const uint4*)(XB + (size_t)na * 128 + g * 8);
        uint4 sb2 = *(const uint4*)(XB + (size_t)nb * 128 + g * 8);
        int r0 = e + 16 + slot, r1 = e + 20 + slot;
        int ma = 0, mb = 0;
        float mAa = 0.f, mBa = 0.f, mAb = 0.f, mBb = 0.f;
        if (r0 < end) { ma = csr[r0]; mAa = ecA[r0]; mBa = ecB[r0]; }
        if (r1 < end) { mb = csr[r1]; mAb = ecA[r1]; mBb = ecB[r1]; }
        fma8(ra, cAa, aA); fma8(rb, cAb, aA);
        fma8(sa, cBa, aB); fma8(sb, cBb, aB);
        ra = ra2; rb = rb2; sa = sa2; sb = sb2;
        cAa = nAa; cBa = nBa; cAb = nAb; cBb = nBb;
        na = ma; nb = mb;
        nAa = mAa; nBa = mBa; nAb = mAb; nBb = mBb;
    }
#pragma unroll
    for (int j = 0; j < 8; j++) {
        aA[j] += __shfl_xor(aA[j], 16); aA[j] += __shfl_xor(aA[j], 32);
        aB[j] += __shfl_xor(aB[j], 16); aB[j] += __shfl_xor(aB[j], 32);
    }
    {
        float c = dinvl[node]; c *= c;
        uint4 xs = *(const uint4*)(XB + (size_t)node * 128 + g * 8);
        fma8(xs, c, aB);
    }
    if (lane < 16) {
        float oA[8], oB[8];
#pragma unroll
        for (int j = 0; j < 8; j++) { oA[j] = -aA[j]; oB[j] = aB[j]; }
        size_t ofs = (size_t)node * 128 + g * 8;
        *(uint4*)(OutA + ofs) = pack8(oA);
        *(uint4*)(OutB + ofs) = pack8(oB);
    }
}

// ---------- device: attention with fused skip-add (+relu), software-pipelined ----------
__device__ __forceinline__ void gt_attn_dev(const ushort_t* __restrict__ Qb,
                                            const ushort_t* __restrict__ KV,
                                            const int* __restrict__ rowptr, const int* __restrict__ csr,
                                            const ushort_t* __restrict__ sk, int relu,
                                            ushort_t* __restrict__ Outb, int M, int bx)
{
    const float SCL = 0.17677669529663689f * 1.4426950408889634f;
    int node = bx * 4 + (threadIdx.x >> 6);
    int lane = threadIdx.x & 63;
    if (node >= M) return;
    int beg = rowptr[node], end = rowptr[node + 1];
    int slot = lane >> 4, g = lane & 15;
    uint4 qv = *(const uint4*)(Qb + (size_t)node * 128 + g * 8);
    float qf[8];
    unpack8(qv, qf);
#pragma unroll
    for (int j = 0; j < 8; j++) qf[j] *= SCL;
    float ax[8] = {0, 0, 0, 0, 0, 0, 0, 0};
    float den = 0.f;

    bool va = false, vb = false;
    int na = 0, nb = 0;
    bool wa = false, wb = false;
    uint4 kA, kB, uA, uB;
    {
        int r0 = beg + slot, r1 = beg + 4 + slot;
        va = r0 < end; vb = r1 < end;
        int ia = va ? csr[r0] : 0;
        int ib = vb ? csr[r1] : 0;
        const ushort_t* p0 = KV + (size_t)ia * 256 + g * 8;
        const ushort_t* p1 = KV + (size_t)ib * 256 + g * 8;
        kA = *(const uint4*)p0; uA = *(const uint4*)(p0 + 128);
        kB = *(const uint4*)p1; uB = *(const uint4*)(p1 + 128);
    }
    {
        int r0 = beg + 8 + slot, r1 = beg + 12 + slot;
        wa = r0 < end; wb = r1 < end;
        na = wa ? csr[r0] : 0;
        nb = wb ? csr[r1] : 0;
    }
    for (int e = beg; e < end; e += 8) {
        const ushort_t* p0 = KV + (size_t)na * 256 + g * 8;
        const ushort_t* p1 = KV + (size_t)nb * 256 + g * 8;
        uint4 kA2 = *(const uint4*)p0;
        uint4 uA2 = *(const uint4*)(p0 + 128);
        uint4 kB2 = *(const uint4*)p1;
        uint4 uB2 = *(const uint4*)(p1 + 128);
        int r0 = e + 16 + slot, r1 = e + 20 + slot;
        bool xa = r0 < end, xb = r1 < end;
        int ma = xa ? csr[r0] : 0;
        int mb = xb ? csr[r1] : 0;
        float d0 = dot8(kA, qf);
        float d1 = dot8(kB, qf);
        d0 += __shfl_xor(d0, 1); d0 += __shfl_xor(d0, 2);
        d1 += __shfl_xor(d1, 1); d1 += __shfl_xor(d1, 2);
        float w0 = va ? exp2f(fminf(d0, 80.f)) : 0.f;
        float w1 = vb ? exp2f(fminf(d1, 80.f)) : 0.f;
        den += w0 + w1;
        fma8(uA, w0, ax);
        fma8(uB, w1, ax);
        kA = kA2; kB = kB2; uA = uA2; uB = uB2;
        va = wa; vb = wb;
        wa = xa; wb = xb; na = ma; nb = mb;
    }
#pragma unroll
    for (int j = 0; j < 8; j++) {
        ax[j] += __shfl_xor(ax[j], 16); ax[j] += __shfl_xor(ax[j], 32);
    }
    den += __shfl_xor(den, 16); den += __shfl_xor(den, 32);
    float dd = fmaxf(den, 1e-9f);
    if (lane < 16) {
        uint4 sv = *(const uint4*)(sk + (size_t)node * 128 + g * 8);
        float sf[8];
        unpack8(sv, sf);
        float o[8];
#pragma unroll
        for (int j = 0; j < 8; j++) {
            float v = ax[j] / dd + sf[j];
            o[j] = relu ? fmaxf(v, 0.f) : v;
        }
        *(uint4*)(Outb + (size_t)node * 128 + g * 8) = pack8(o);
    }
}

// ---------- merged: gather2 + MLP-L1 (no LDS) ----------
__global__ void flatA_kernel(const ushort_t* __restrict__ hb,
                             ushort_t* __restrict__ x1, ushort_t* __restrict__ x2,
                             const int* __restrict__ rowptr, const int* __restrict__ csr,
                             const float* __restrict__ ecA, const float* __restrict__ ecB,
                             const float* __restrict__ dinvl, int N,
                             const ushort_t* __restrict__ wmlp1, ushort_t* __restrict__ xm,
                             const float* __restrict__ b18)
{
    int bx = blockIdx.x;
    int gN4 = (N + 3) >> 2;
    if (bx < gN4) {
        gather2_dev(hb, x1, x2, rowptr, csr, ecA, ecB, dinvl, N, bx);
    } else {
        int w = (bx - gN4) * 4 + (threadIdx.x >> 6);
        gemm_wv_dev(hb, wmlp1, xm, N, b18, 1, w, threadIdx.x & 63);
    }
}

// ---------- merged LDS GEMMs A: Q,K,V,S panels + Cheb dual1 + GCN1 ----------
__global__ __launch_bounds__(256)
void megaA_kernel(const ushort_t* __restrict__ hb,
                  const ushort_t* __restrict__ wqkvs,
                  ushort_t* __restrict__ qb, ushort_t* __restrict__ kvb, ushort_t* __restrict__ skb,
                  const float* __restrict__ bq, const float* __restrict__ bk,
                  const float* __restrict__ bv, const float* __restrict__ bs,
                  const ushort_t* __restrict__ x1, const ushort_t* __restrict__ wch0,
                  const ushort_t* __restrict__ wch1, ushort_t* __restrict__ x0,
                  const float* __restrict__ bch,
                  const ushort_t* __restrict__ x2, const ushort_t* __restrict__ wgcn,
                  ushort_t* __restrict__ xg1, const float* __restrict__ bgcn,
                  int M)
{
    __shared__ ushort_t As[64][40];
    __shared__ ushort_t Bs[128][40];
    int y = blockIdx.y, bx = blockIdx.x;
    const size_t PS = (size_t)128 * 128;   // weight panel stride
    if (y == 0) gemm_bfs_dev(As, Bs, hb, wqkvs, qb, 128, M, bq, bx);
    else if (y == 1) gemm_bfs_dev(As, Bs, hb, wqkvs + PS, kvb, 256, M, bk, bx);
    else if (y == 2) gemm_bfs_dev(As, Bs, hb, wqkvs + 2 * PS, kvb + 128, 256, M, bv, bx);
    else if (y == 3) gemm_bfs_dev(As, Bs, hb, wqkvs + 3 * PS, skb, 128, M, bs, bx);
    else if (y == 4) gemm_dual_dev(As, Bs, hb, wch0, x1, wch1, x0, M, bch, 1, bx);
    else gemm_bf_dev<128>(As, Bs, x2, wgcn, xg1, M, bgcn, 1, bx);
}

// ---------- merged: attn1 + gather_l2 (no LDS) ----------
__global__ void flatB_kernel(const ushort_t* __restrict__ qb, const ushort_t* __restrict__ kvb,
                             const int* __restrict__ rowptr, const int* __restrict__ csr,
                             const ushort_t* __restrict__ skb, ushort_t* __restrict__ aout,
                             const ushort_t* __restrict__ x0, const ushort_t* __restrict__ xg1,
                             ushort_t* __restrict__ x3, ushort_t* __restrict__ x2,
                             const float* __restrict__ ecA, const float* __restrict__ ecB,
                             const float* __restrict__ dinvl, int N)
{
    int bx = blockIdx.x;
    int gN4 = (N + 3) >> 2;
    if (bx < gN4) gt_attn_dev(qb, kvb, rowptr, csr, skb, 1, aout, N, bx);
    else gather_l2_dev(x0, xg1, x3, x2, rowptr, csr, ecA, ecB, dinvl, N, bx - gN4);
}

// ---------- merged LDS GEMMs B: Q,K,V,S panels + Cheb dual2 + GCN2 + MLP2 ----------
__global__ __launch_bounds__(256)
void megaB_kernel(const ushort_t* __restrict__ x1,
                  const ushort_t* __restrict__ wqkvs,
                  ushort_t* __restrict__ qb, ushort_t* __restrict__ kvb, ushort_t* __restrict__ skb,
                  const float* __restrict__ bq, const float* __restrict__ bk,
                  const float* __restrict__ bv, const float* __restrict__ bs,
                  const ushort_t* __restrict__ x0, const ushort_t* __restrict__ wch0,
                  const ushort_t* __restrict__ x3, const ushort_t* __restrict__ wch1,
                  ushort_t* __restrict__ e1b, const float* __restrict__ bch,
                  const ushort_t* __restrict__ x2, const ushort_t* __restrict__ wgcn,
                  ushort_t* __restrict__ e3b, const float* __restrict__ bgcn,
                  const ushort_t* __restrict__ xm, const ushort_t* __restrict__ wmlp2,
                  ushort_t* __restrict__ e0b, const float* __restrict__ bmlp2,
                  int M)
{
    __shared__ ushort_t As[64][40];
    __shared__ ushort_t Bs[128][40];
    int y = blockIdx.y, bx = blockIdx.x;
    const size_t PS = (size_t)128 * 128;
    if (y == 0) gemm_bfs_dev(As, Bs, x1, wqkvs, qb, 128, M, bq, bx);
    else if (y == 1) gemm_bfs_dev(As, Bs, x1, wqkvs + PS, kvb, 256, M, bk, bx);
    else if (y == 2) gemm_bfs_dev(As, Bs, x1, wqkvs + 2 * PS, kvb + 128, 256, M, bv, bx);
    else if (y == 3) gemm_bfs_dev(As, Bs, x1, wqkvs + 3 * PS, skb, 128, M, bs, bx);
    else if (y == 4) gemm_dual_dev(As, Bs, x0, wch0, x3, wch1, e1b, M, bch, 0, bx);
    else if (y == 5) gemm_bf_dev<128>(As, Bs, x2, wgcn, e3b, M, bgcn, 0, bx);
    else gemm_bf_dev<128>(As, Bs, xm, wmlp2, e0b, M, bmlp2, 0, bx);
}

// ---------- attention layer 2 (standalone) ----------
__global__ void gt_attn2_kernel(const ushort_t* __restrict__ Qb, const ushort_t* __restrict__ KV,
                                const int* __restrict__ rowptr, const int* __restrict__ csr,
                                const ushort_t* __restrict__ sk,
                                ushort_t* __restrict__ Outb, int M)
{
    gt_attn_dev(Qb, KV, rowptr, csr, sk, 0, Outb, M, blockIdx.x);
}

// ---------- fused combine + pool phase 1 ----------
__global__ void pool_combine_kernel(const ushort_t* __restrict__ hb,
                                    const ushort_t* __restrict__ e0, const ushort_t* __restrict__ e1,
                                    const ushort_t* __restrict__ e2, const ushort_t* __restrict__ e3,
                                    const float* __restrict__ gates,
                                    const float* __restrict__ png, const float* __restrict__ pnb,
                                    const float* __restrict__ esc,
                                    const int* __restrict__ bstart, const int* __restrict__ bend,
                                    float* __restrict__ partial)
{
    int b = blockIdx.x, c = blockIdx.y;
    int lane = threadIdx.x;   // 64
    int s0 = bstart[b], e0i = bend[b];
    const ushort_t* eps[4] = {e0, e1, e2, e3};
    float ga[4], gb[4], ba[4], bb[4], es[4];
#pragma unroll
    for (int ee = 0; ee < 4; ee++) {
        ga[ee] = png[ee * 128 + lane * 2];
        gb[ee] = png[ee * 128 + lane * 2 + 1];
        ba[ee] = pnb[ee * 128 + lane * 2];
        bb[ee] = pnb[ee * 128 + lane * 2 + 1];
        es[ee] = esc[ee];
    }
    float sx = 0.f, sy = 0.f;
    for (int n = s0 + c; n < e0i; n += PCH) {
        size_t ofs = (size_t)n * 128 + lane * 2;
        float4 gg = *(const float4*)(gates + (size_t)n * 4);
        float gv[4] = {gg.x, gg.y, gg.z, gg.w};
        unsigned int hu = *(const unsigned int*)(hb + ofs);
        float ox = bf2f(hu & 0xffff), oy = bf2f(hu >> 16);
#pragma unroll
        for (int ee = 0; ee < 4; ee++) {
            unsigned int u = *(const unsigned int*)(eps[ee] + ofs);
            float vx = bf2f(u & 0xffff), vy = bf2f(u >> 16);
            float su = vx + vy, sq = vx * vx + vy * vy;
#pragma unroll
            for (int off = 32; off; off >>= 1) { su += __shfl_xor(su, off); sq += __shfl_xor(sq, off); }
            float mean = su * (1.f / 128.f);
            float var = sq * (1.f / 128.f) - mean * mean;
            float inv = rsqrtf(var + 1e-5f);
            float cc = es[ee] * gv[ee];
            ox = fmaf(cc, (vx - mean) * inv * ga[ee] + ba[ee], ox);
            oy = fmaf(cc, (vy - mean) * inv * gb[ee] + bb[ee], oy);
        }
        sx += ox; sy += oy;
    }
    *(float2*)(partial + ((size_t)b * PCH + c) * 128 + lane * 2) = make_float2(sx, sy);
}

// ---------- classification head (with fused pool reduce) ----------
__global__ void head_kernel(const float* __restrict__ partial,
                            const int* __restrict__ bstart, const int* __restrict__ bend,
                            const float* __restrict__ h1W, const float* __restrict__ h1b,
                            const float* __restrict__ h1g, const float* __restrict__ h1be,
                            const float* __restrict__ h2W, const float* __restrict__ h2b,
                            const float* __restrict__ h2g, const float* __restrict__ h2be,
                            const float* __restrict__ h3W, const float* __restrict__ h3b,
                            const float* __restrict__ lbias,
                            float* __restrict__ out, int B)
{
    __shared__ float p[128], z[128];
    int b = blockIdx.x, t = threadIdx.x;
    float sum = 0.f;
#pragma unroll
    for (int c = 0; c < PCH; c++) sum += partial[((size_t)b * PCH + c) * 128 + t];
    float cnt = fmaxf((float)(bend[b] - bstart[b]), 1.f);
    p[t] = sum / cnt;
    __syncthreads();
    float a = h1b[t];
    for (int k = 0; k < 128; k++) a = fmaf(p[k], h1W[k * 128 + t], a);
    z[t] = a;
    __syncthreads();
    float s = 0.f, sq = 0.f;
    for (int k = 0; k < 128; k++) { float x = z[k]; s += x; sq += x * x; }
    float mean = s * (1.f / 128.f), var = sq * (1.f / 128.f) - mean * mean;
    float y = fmaxf((a - mean) * rsqrtf(var + 1e-5f) * h1g[t] + h1be[t], 0.f);
    __syncthreads();
    z[t] = y;
    __syncthreads();
    float a2 = 0.f;
    if (t < 64) {
        a2 = h2b[t];
        for (int k = 0; k < 128; k++) a2 = fmaf(z[k], h2W[k * 64 + t], a2);
    }
    __syncthreads();
    if (t < 64) p[t] = a2;
    __syncthreads();
    if (t < 2) {
        float s2 = 0.f, sq2 = 0.f;
        for (int k = 0; k < 64; k++) { float x = p[k]; s2 += x; sq2 += x * x; }
        float mean2 = s2 * (1.f / 64.f), var2 = sq2 * (1.f / 64.f) - mean2 * mean2;
        float inv2 = rsqrtf(var2 + 1e-5f);
        float o = h3b[t] + lbias[t];
        for (int k = 0; k < 64; k++) {
            float zc = fmaxf((p[k] - mean2) * inv2 * h2g[k] + h2be[k], 0.f);
            o = fmaf(zc, h3W[k * 2 + t], o);
        }
        out[b * 2 + t] = o;
    }
}

// ---------------- launch ----------------
extern "C" void kernel_launch(void* const* d_in, const int* in_sizes, int n_in,
                              void* d_out, int out_size, void* d_ws, size_t ws_size,
                              hipStream_t stream)
{
    (void)ws_size; (void)n_in;
    const int N = in_sizes[3];
    const int E = in_sizes[2] / 2;
    const int B = out_size / 2;

    const int* ei = (const int*)d_in[2];
    const int* src = ei;
    const int* dst = ei + E;
    const int* batch = (const int*)d_in[3];

    const float* W[47];
    for (int i = 0; i < 47; i++) W[i] = (const float*)d_in[i];

    size_t fN = (size_t)N;
    float* gates    = (float*)d_ws;                    // 4N
    float* dinv     = gates + 4 * fN;                  // N
    float* dinvl    = dinv + fN;                       // N
    float* partial  = dinvl + fN;                      // 128*B*PCH
    float* logitsA  = partial + (size_t)128 * B * PCH;
    float* logitsB  = logitsA + 4 * fN;
    ushort_t* hb  = (ushort_t*)(logitsB + 4 * fN);
    ushort_t* e0b = hb + 128 * fN;
    ushort_t* e1b = e0b + 128 * fN;
    ushort_t* e2b = e1b + 128 * fN;
    ushort_t* e3b = e2b + 128 * fN;
    ushort_t* x0  = e3b + 128 * fN;
    ushort_t* x1  = x0 + 128 * fN;
    ushort_t* x2  = x1 + 128 * fN;
    ushort_t* x3  = x2 + 128 * fN;
    ushort_t* xm  = x3 + 128 * fN;
    ushort_t* xg1 = xm + 128 * fN;
    ushort_t* skb = xg1 + 128 * fN;
    ushort_t* qb  = skb + 128 * fN;
    ushort_t* kvb = qb + 128 * fN;           // 256N
    ushort_t* hrb = kvb + 256 * fN;          // 256N bf16 (router features)
    ushort_t* wt  = hrb + 256 * fN;
    WtPack wp;
    const float* wsrc[NWT] = {
        W[4], W[8], W[12], W[17], W[19],
        W[21], W[21] + 16384, W[21] + 32768, W[21] + 49152,
        W[23], W[25], W[27], W[29],                                     // q1,k1,v1,s1 (contiguous 512)
        W[23] + 16384, W[25] + 16384, W[27] + 16384, W[29] + 16384,     // q2,k2,v2,s2
        W[31], W[31] + 16384
    };
    const int wk[NWT] = {200, 128, 256, 128, 128,
                         128, 128, 128, 128,
                         128, 128, 128, 128,
                         128, 128, 128, 128,
                         128, 128};
    unsigned long long woff[NWT];
    unsigned long long acc_off = 0;
    for (int i = 0; i < NWT; i++) {
        wp.src[i] = wsrc[i];
        wp.K[i] = wk[i];
        wp.off[i] = acc_off;
        woff[i] = acc_off;
        acc_off += (unsigned long long)128 * wk[i];
    }
    int* degi   = (int*)(wt + acc_off + 8);
    int* cursor = degi + N;
    int* rowptr = cursor + N;
    int* csr    = rowptr + (N + 1);
    int* bstart = csr + E;
    int* bend   = bstart + B;
    int* bsum   = bend + B;
    float* ecA  = (float*)(bsum + 256);      // E floats (CSR-ordered sym-norm coefs)
    float* ecB  = ecA + E;                   // E floats (CSR-ordered GCN coefs)

    dim3 blk(256);
    int gN4 = (N + 3) / 4;
    int gG = (N + 63) / 64;
    int RT = (N + 15) / 16;
    int nsb = (N + SCH - 1) / SCH;
    int nseg = (N + 255) / 256;
    int nedge = (E + 255) / 256;

    // zero degi+cursor and bstart+bend (stream-ordered, graph-capturable)
    hipMemsetAsync(degi, 0, (size_t)2 * N * sizeof(int), stream);
    hipMemsetAsync(bstart, 0, (size_t)2 * B * sizeof(int), stream);

    // L0: wconv + seg_bounds + edge_deg
    setup_mega_kernel<<<dim3(608 + nseg + nedge), blk, 0, stream>>>(
        wp, wt, batch, bstart, bend, N, dst, degi, E);
    // L1/L2: scan phases
    scan1_kernel<<<dim3(nsb), blk, 0, stream>>>(degi, rowptr, bsum, N);
    scan2_kernel<<<1, blk, 0, stream>>>(bsum, nsb);
    // L3: scan3 + both encoder GEMMs (independent)
    EncCfg c0 = {W[0], 200, 200, wt + woff[0], hrb, W[5], W[6], W[7], W[16], logitsA};
    EncCfg c1 = {W[1], 128, 128, wt + woff[1], hrb + 128, W[9], W[10], W[11], W[16] + 512, logitsB};
    scan3_enc_kernel<<<dim3(nseg + 2 * gG), blk, 0, stream>>>(
        rowptr, bsum, degi, dinv, dinvl, N, c0, c1);
    // L4: fuse GEMM (K=256)+LN+ReLU -> hb  ||  csr_fill  ||  router top-k
    ln_csr_topk_kernel<<<dim3(gG + nedge + nseg), blk, 0, stream>>>(
        hrb, wt + woff[2], hb, N, W[13], W[14], W[15],
        src, dst, rowptr, cursor, csr, dinv, dinvl, ecA, ecB, E,
        logitsA, logitsB, gates);
    // L5: gather2 + MLP-L1 (both read hb only)
    flatA_kernel<<<dim3(gN4 + RT), blk, 0, stream>>>(hb, x1, x2, rowptr, csr, ecA, ecB,
                                                     dinvl, N, wt + woff[3], xm, W[18]);
    // L6: Q/K/V/S panels (layer1) + Cheb dual1 + GCN1
    megaA_kernel<<<dim3(gG, 6), blk, 0, stream>>>(
        hb, wt + woff[9], qb, kvb, skb, W[24], W[26], W[28], W[30],
        x1, wt + woff[5], wt + woff[6], x0, W[22],
        x2, wt + woff[17], xg1, W[32], N);
    // L7: attn1 + gather_l2
    flatB_kernel<<<dim3(2 * gN4), blk, 0, stream>>>(
        qb, kvb, rowptr, csr, skb, x1,
        x0, xg1, x3, x2, ecA, ecB, dinvl, N);
    // L8: QKVS2 panels + Cheb dual2 + GCN2 + MLP-L2
    megaB_kernel<<<dim3(gG, 7), blk, 0, stream>>>(
        x1, wt + woff[13], qb, kvb, skb,
        W[24] + 128, W[26] + 128, W[28] + 128, W[30] + 128,
        x0, wt + woff[7], x3, wt + woff[8], e1b, W[22] + 128,
        x2, wt + woff[18], e3b, W[32] + 128,
        xm, wt + woff[4], e0b, W[20], N);
    // L9: attn2 -> e2b
    gt_attn2_kernel<<<dim3(gN4), blk, 0, stream>>>(qb, kvb, rowptr, csr, skb, e2b, N);
    // L10/L11: combine+pool + head
    pool_combine_kernel<<<dim3(B, PCH), dim3(64), 0, stream>>>(
        hb, e0b, e1b, e2b, e3b, gates, W[33], W[34], W[35], bstart, bend, partial);
    head_kernel<<<dim3(B), dim3(128), 0, stream>>>(partial, bstart, bend,
        W[36], W[37], W[38], W[39],
        W[40], W[41], W[42], W[43],
        W[44], W[45], W[46],
        (float*)d_out, B);
}